// Round 1
// baseline (5725.193 us; speedup 1.0000x reference)
//
#include <hip/hip_runtime.h>
#include <math.h>

typedef unsigned short u16;
typedef float f32x4 __attribute__((ext_vector_type(4)));
typedef __bf16 bf16x8 __attribute__((ext_vector_type(8)));
typedef u16 u16x8 __attribute__((ext_vector_type(8)));
typedef u16 u16x4 __attribute__((ext_vector_type(4)));

#define L_SEQ 256
#define BSZ 32
#define HID 1024
#define NIN 1024
#define VOC 10000
#define G4 4096
#define MROWS 8192  // L_SEQ*BSZ

__device__ __forceinline__ u16 f2bf(float f) {
    unsigned u = __float_as_uint(f);
    unsigned r = u + 0x7FFFu + ((u >> 16) & 1u);
    return (u16)(r >> 16);
}

// ---------------- converters ----------------
__global__ __launch_bounds__(256) void cvt_bf16_kernel(const float* __restrict__ in,
                                                       u16* __restrict__ out, int n4) {
    int idx = blockIdx.x * 256 + threadIdx.x;
    if (idx < n4) {
        f32x4 v = *(const f32x4*)(in + (size_t)idx * 4);
        u16x4 o = {f2bf(v.x), f2bf(v.y), f2bf(v.z), f2bf(v.w)};
        *(u16x4*)(out + (size_t)idx * 4) = o;
    }
}

// gather emb rows -> bf16 A matrix [8192][1024]
__global__ __launch_bounds__(256) void gather_emb_kernel(const int* __restrict__ ids,
                                                         const float* __restrict__ emb_w,
                                                         u16* __restrict__ out) {
    int m = blockIdx.x;
    int id = ids[m];
    const float* src = emb_w + (size_t)id * NIN;
    u16* dst = out + (size_t)m * NIN;
    int t = threadIdx.x;
    f32x4 v = *(const f32x4*)(src + t * 4);
    u16x4 o = {f2bf(v.x), f2bf(v.y), f2bf(v.z), f2bf(v.w)};
    *(u16x4*)(dst + t * 4) = o;
}

// ---------------- 128x128 MFMA GEMM: C[M][N] = A[M][K] * B[N][K]^T (+bias) ----------------
__global__ __launch_bounds__(256) void gemm_bt_kernel(const u16* __restrict__ A,
                                                      const u16* __restrict__ B,
                                                      float* __restrict__ C,
                                                      const float* __restrict__ bias,
                                                      int M, int N, int K) {
    int m0 = blockIdx.x * 128;
    int n0 = blockIdx.y * 128;
    __shared__ alignas(16) u16 As[128][40];
    __shared__ alignas(16) u16 Bs[128][40];
    int t = threadIdx.x;
    int lane = t & 63, wave = t >> 6;
    int wr = wave >> 1, wc = wave & 1;
    int l15 = lane & 15, l4 = lane >> 4;

    f32x4 acc[4][4];
    f32x4 zv = {0.f, 0.f, 0.f, 0.f};
    for (int mi = 0; mi < 4; ++mi)
        for (int ni = 0; ni < 4; ++ni) acc[mi][ni] = zv;

    for (int k0 = 0; k0 < K; k0 += 32) {
        for (int s = 0; s < 2; ++s) {
            int task = t + s * 256;
            int row = task >> 2, kof = (task & 3) * 8;
            u16x8 av = *(const u16x8*)(A + (size_t)(m0 + row) * K + k0 + kof);
            *(u16x8*)(&As[row][kof]) = av;
            int brow = n0 + row;
            u16x8 bv = {0, 0, 0, 0, 0, 0, 0, 0};
            if (brow < N) bv = *(const u16x8*)(B + (size_t)brow * K + k0 + kof);
            *(u16x8*)(&Bs[row][kof]) = bv;
        }
        __syncthreads();
        bf16x8 af[4], bfr[4];
        for (int mi = 0; mi < 4; ++mi)
            af[mi] = __builtin_bit_cast(bf16x8, *(const u16x8*)(&As[wr * 64 + mi * 16 + l15][l4 * 8]));
        for (int ni = 0; ni < 4; ++ni)
            bfr[ni] = __builtin_bit_cast(bf16x8, *(const u16x8*)(&Bs[wc * 64 + ni * 16 + l15][l4 * 8]));
        for (int mi = 0; mi < 4; ++mi)
            for (int ni = 0; ni < 4; ++ni)
                acc[mi][ni] = __builtin_amdgcn_mfma_f32_16x16x32_bf16(af[mi], bfr[ni], acc[mi][ni], 0, 0, 0);
        __syncthreads();
    }

    for (int mi = 0; mi < 4; ++mi)
        for (int ni = 0; ni < 4; ++ni) {
            int col = n0 + wc * 64 + ni * 16 + l15;
            if (col < N) {
                float bb = bias ? bias[col] : 0.f;
                int rbase = m0 + wr * 64 + mi * 16 + l4 * 4;
                for (int r = 0; r < 4; ++r)
                    C[(size_t)(rbase + r) * N + col] = acc[mi][ni][r] + bb;
            }
        }
}

// ---------------- per-step fused: gates = gx + h@w_hh^T, LSTM cell, a/b partials ----------------
__global__ __launch_bounds__(256) void lstm_step_kernel(const u16* __restrict__ h_bf,
                                                        const u16* __restrict__ w_hh_bf,
                                                        const float* __restrict__ gx,
                                                        const float* __restrict__ Wv,
                                                        const float* __restrict__ Uv,
                                                        float* __restrict__ hist,
                                                        float* __restrict__ c,
                                                        u16* __restrict__ h_bf_out,
                                                        float* __restrict__ a_arr,
                                                        float* __restrict__ b_arr,
                                                        int i) {
    int kc = blockIdx.x;  // k-chunk of 32
    __shared__ alignas(16) u16 As[32][40];
    __shared__ alignas(16) u16 Bs[128][40];
    __shared__ float gsm[32][128];
    __shared__ float paS[32][32];
    __shared__ float puS[32][32];
    int t = threadIdx.x;
    int lane = t & 63, w = t >> 6;
    int l15 = lane & 15, l4 = lane >> 4;

    f32x4 acc[2][2];
    f32x4 zv = {0.f, 0.f, 0.f, 0.f};
    acc[0][0] = zv; acc[0][1] = zv; acc[1][0] = zv; acc[1][1] = zv;

    for (int k0 = 0; k0 < HID; k0 += 32) {
        if (t < 128) {
            int row = t >> 2, kof = (t & 3) * 8;
            *(u16x8*)(&As[row][kof]) = *(const u16x8*)(h_bf + row * HID + k0 + kof);
        }
        for (int s = 0; s < 2; ++s) {
            int task = t + s * 256;
            int row = task >> 2, kof = (task & 3) * 8;
            int g = row >> 5, kl = row & 31;
            const u16* src = w_hh_bf + (size_t)(g * HID + kc * 32 + kl) * HID + k0 + kof;
            *(u16x8*)(&Bs[row][kof]) = *(const u16x8*)src;
        }
        __syncthreads();
        bf16x8 af[2], bfr[2];
        for (int mi = 0; mi < 2; ++mi)
            af[mi] = __builtin_bit_cast(bf16x8, *(const u16x8*)(&As[mi * 16 + l15][l4 * 8]));
        for (int ni = 0; ni < 2; ++ni)
            bfr[ni] = __builtin_bit_cast(bf16x8, *(const u16x8*)(&Bs[(w * 2 + ni) * 16 + l15][l4 * 8]));
        for (int mi = 0; mi < 2; ++mi)
            for (int ni = 0; ni < 2; ++ni)
                acc[mi][ni] = __builtin_amdgcn_mfma_f32_16x16x32_bf16(af[mi], bfr[ni], acc[mi][ni], 0, 0, 0);
        __syncthreads();
    }
    for (int mi = 0; mi < 2; ++mi)
        for (int ni = 0; ni < 2; ++ni)
            for (int r = 0; r < 4; ++r)
                gsm[mi * 16 + l4 * 4 + r][(w * 2 + ni) * 16 + l15] = acc[mi][ni][r];
    __syncthreads();

    for (int r = 0; r < 4; ++r) {
        int oid = t + r * 256;
        int b = oid >> 5, kl = oid & 31;
        int kg = kc * 32 + kl;
        size_t gxrow = (size_t)(i * BSZ + b) * G4;
        float ig = gsm[b][kl] + gx[gxrow + kg];
        float fg = gsm[b][32 + kl] + gx[gxrow + HID + kg];
        float gg = gsm[b][64 + kl] + gx[gxrow + 2 * HID + kg];
        float og = gsm[b][96 + kl] + gx[gxrow + 3 * HID + kg];
        float si = 1.f / (1.f + expf(-ig));
        float sf = 1.f / (1.f + expf(-fg));
        float so = 1.f / (1.f + expf(-og));
        float tg = tanhf(gg);
        float cn = sf * c[b * HID + kg] + si * tg;
        float hn = so * tanhf(cn);
        c[b * HID + kg] = cn;
        hist[((size_t)i * BSZ + b) * HID + kg] = hn;
        h_bf_out[b * HID + kg] = f2bf(hn);
        paS[b][kl] = hn * Wv[kg];
        puS[b][kl] = hn * Uv[kg];
    }
    __syncthreads();
    if (t < BSZ) {
        float sa = 0.f, su = 0.f;
        for (int kl = 0; kl < 32; ++kl) { sa += paS[t][kl]; su += puS[t][kl]; }
        atomicAdd(&a_arr[i * BSZ + t], sa);
        atomicAdd(&b_arr[i * BSZ + t], su);
    }
}

// ---------------- attention: 8 queries per block, one batch per block.y ----------------
__global__ __launch_bounds__(256) void attn_kernel(const float* __restrict__ a_arr,
                                                   const float* __restrict__ b_arr,
                                                   const float* __restrict__ hist,
                                                   u16* __restrict__ ctx_bf) {
    int b = blockIdx.y;
    int i0 = blockIdx.x * 8;
    int t = threadIdx.x;
    __shared__ float att[8][256];
    __shared__ float red[256];

    float bt = b_arr[t * BSZ + b];
    for (int q = 0; q < 8; ++q) {
        int iq = i0 + q;
        att[q][t] = (t <= iq) ? tanhf(a_arr[iq * BSZ + b] + bt) : -INFINITY;
    }
    __syncthreads();
    for (int q = 0; q < 8; ++q) {
        int iq = i0 + q;
        red[t] = att[q][t];
        __syncthreads();
        for (int s = 128; s > 0; s >>= 1) {
            if (t < s) red[t] = fmaxf(red[t], red[t + s]);
            __syncthreads();
        }
        float m = red[0];
        __syncthreads();
        float e = (t <= iq) ? expf(att[q][t] - m) : 0.f;
        red[t] = e;
        __syncthreads();
        for (int s = 128; s > 0; s >>= 1) {
            if (t < s) red[t] += red[t + s];
            __syncthreads();
        }
        float sum = red[0];
        __syncthreads();
        att[q][t] = e / sum;
        __syncthreads();
    }

    int hc = t * 4;
    f32x4 accq[8];
    f32x4 zv = {0.f, 0.f, 0.f, 0.f};
    for (int q = 0; q < 8; ++q) accq[q] = zv;
    int imax = i0 + 7;
    for (int t2 = 0; t2 <= imax; ++t2) {
        f32x4 hv = *(const f32x4*)(hist + ((size_t)t2 * BSZ + b) * HID + hc);
        for (int q = 0; q < 8; ++q) accq[q] += hv * att[q][t2];
    }
    for (int q = 0; q < 8; ++q) {
        size_t row = (size_t)(i0 + q) * BSZ + b;
        u16x4 o = {f2bf(accq[q].x), f2bf(accq[q].y), f2bf(accq[q].z), f2bf(accq[q].w)};
        *(u16x4*)(ctx_bf + row * HID + hc) = o;
    }
}

// ---------------- in-place log_softmax over rows of [8192][10000] ----------------
__global__ __launch_bounds__(256) void logsoftmax_kernel(float* __restrict__ x, int V) {
    int row = blockIdx.x;
    float* p = x + (size_t)row * V;
    __shared__ float red[256];
    int t = threadIdx.x;
    float m = -INFINITY;
    for (int j = t; j < V; j += 256) m = fmaxf(m, p[j]);
    red[t] = m;
    __syncthreads();
    for (int s = 128; s > 0; s >>= 1) {
        if (t < s) red[t] = fmaxf(red[t], red[t + s]);
        __syncthreads();
    }
    m = red[0];
    __syncthreads();
    float sum = 0.f;
    for (int j = t; j < V; j += 256) sum += expf(p[j] - m);
    red[t] = sum;
    __syncthreads();
    for (int s = 128; s > 0; s >>= 1) {
        if (t < s) red[t] += red[t + s];
        __syncthreads();
    }
    float lse = m + logf(red[0]);
    for (int j = t; j < V; j += 256) p[j] = p[j] - lse;
}

extern "C" void kernel_launch(void* const* d_in, const int* in_sizes, int n_in,
                              void* d_out, int out_size, void* d_ws, size_t ws_size,
                              hipStream_t stream) {
    const int* ids = (const int*)d_in[0];
    const float* h0 = (const float*)d_in[1];
    const float* c0 = (const float*)d_in[2];
    const float* emb_w = (const float*)d_in[3];
    const float* w_ih = (const float*)d_in[4];
    const float* w_hh = (const float*)d_in[5];
    const float* dec_w = (const float*)d_in[6];
    const float* dec_b = (const float*)d_in[7];
    const float* Wv = (const float*)d_in[8];
    const float* Uv = (const float*)d_in[9];

    char* p = (char*)d_ws;
    auto alloc = [&](size_t bytes) {
        void* r = (void*)p;
        p += (bytes + 255) & ~(size_t)255;
        return r;
    };
    u16* w_ih_bf = (u16*)alloc((size_t)G4 * NIN * 2);
    u16* w_hh_bf = (u16*)alloc((size_t)G4 * HID * 2);
    u16* dec_w_bf = (u16*)alloc((size_t)VOC * HID * 2);
    u16* A_emb = (u16*)alloc((size_t)MROWS * NIN * 2);
    u16* ctx_bf = (u16*)alloc((size_t)MROWS * HID * 2);
    float* hist = (float*)alloc((size_t)L_SEQ * BSZ * HID * 4);
    float* c_buf = (float*)alloc((size_t)BSZ * HID * 4);
    u16* hbf = (u16*)alloc((size_t)2 * BSZ * HID * 2);
    float* a_arr = (float*)alloc((size_t)L_SEQ * BSZ * 4);
    float* b_arr = (float*)alloc((size_t)L_SEQ * BSZ * 4);

    float* out = (float*)d_out;
    float* gx = out;  // reuse d_out as gx [8192][4096] f32 until logits overwrite it

    // weight conversions
    cvt_bf16_kernel<<<(G4 * NIN / 4 + 255) / 256, 256, 0, stream>>>(w_ih, w_ih_bf, G4 * NIN / 4);
    cvt_bf16_kernel<<<(G4 * HID / 4 + 255) / 256, 256, 0, stream>>>(w_hh, w_hh_bf, G4 * HID / 4);
    cvt_bf16_kernel<<<(VOC * HID / 4 + 255) / 256, 256, 0, stream>>>(dec_w, dec_w_bf, VOC * HID / 4);
    gather_emb_kernel<<<MROWS, 256, 0, stream>>>(ids, emb_w, A_emb);
    cvt_bf16_kernel<<<(BSZ * HID / 4 + 255) / 256, 256, 0, stream>>>(h0, hbf, BSZ * HID / 4);
    hipMemcpyAsync(c_buf, c0, (size_t)BSZ * HID * 4, hipMemcpyDeviceToDevice, stream);
    hipMemsetAsync(a_arr, 0, (size_t)2 * L_SEQ * BSZ * 4, stream);  // a_arr + b_arr contiguous

    // gx = emb @ w_ih^T
    gemm_bt_kernel<<<dim3(MROWS / 128, G4 / 128), 256, 0, stream>>>(A_emb, w_ih_bf, gx, nullptr,
                                                                    MROWS, G4, NIN);
    // recurrence
    for (int i = 0; i < L_SEQ; ++i) {
        const u16* hin = hbf + (size_t)(i & 1) * BSZ * HID;
        u16* hout = hbf + (size_t)((i + 1) & 1) * BSZ * HID;
        lstm_step_kernel<<<32, 256, 0, stream>>>(hin, w_hh_bf, gx, Wv, Uv, hist, c_buf, hout,
                                                 a_arr, b_arr, i);
    }
    // attention -> ctx (bf16)
    attn_kernel<<<dim3(L_SEQ / 8, BSZ), 256, 0, stream>>>(a_arr, b_arr, hist, ctx_bf);
    // logits = ctx @ dec_w^T + dec_b  (into d_out)
    gemm_bt_kernel<<<dim3(MROWS / 128, (VOC + 127) / 128), 256, 0, stream>>>(ctx_bf, dec_w_bf, out,
                                                                             dec_b, MROWS, VOC, HID);
    // in-place log_softmax
    logsoftmax_kernel<<<MROWS, 256, 0, stream>>>(out, VOC);
    // tail outputs: h = hist[255], c = c_buf
    hipMemcpyAsync(out + (size_t)MROWS * VOC, hist + (size_t)255 * BSZ * HID,
                   (size_t)BSZ * HID * 4, hipMemcpyDeviceToDevice, stream);
    hipMemcpyAsync(out + (size_t)MROWS * VOC + BSZ * HID, c_buf,
                   (size_t)BSZ * HID * 4, hipMemcpyDeviceToDevice, stream);
}

// Round 2
// 5349.111 us; speedup vs baseline: 1.0703x; 1.0703x over previous
//
#include <hip/hip_runtime.h>
#include <math.h>

typedef unsigned short u16;
typedef float f32x4 __attribute__((ext_vector_type(4)));
typedef __bf16 bf16x8 __attribute__((ext_vector_type(8)));
typedef u16 u16x8 __attribute__((ext_vector_type(8)));
typedef u16 u16x4 __attribute__((ext_vector_type(4)));

#define L_SEQ 256
#define BSZ 32
#define HID 1024
#define NIN 1024
#define VOC 10000
#define G4 4096
#define MROWS 8192  // L_SEQ*BSZ
#define NB 64       // persistent blocks
#define DPB 16      // h-dims per block

__device__ __forceinline__ u16 f2bf(float f) {
    unsigned u = __float_as_uint(f);
    unsigned r = u + 0x7FFFu + ((u >> 16) & 1u);
    return (u16)(r >> 16);
}

// ---------------- converters ----------------
__global__ __launch_bounds__(256) void cvt_bf16_kernel(const float* __restrict__ in,
                                                       u16* __restrict__ out, int n4) {
    int idx = blockIdx.x * 256 + threadIdx.x;
    if (idx < n4) {
        f32x4 v = *(const f32x4*)(in + (size_t)idx * 4);
        u16x4 o = {f2bf(v.x), f2bf(v.y), f2bf(v.z), f2bf(v.w)};
        *(u16x4*)(out + (size_t)idx * 4) = o;
    }
}

// gather emb rows -> bf16 A matrix [8192][1024]
__global__ __launch_bounds__(256) void gather_emb_kernel(const int* __restrict__ ids,
                                                         const float* __restrict__ emb_w,
                                                         u16* __restrict__ out) {
    int m = blockIdx.x;
    int id = ids[m];
    const float* src = emb_w + (size_t)id * NIN;
    u16* dst = out + (size_t)m * NIN;
    int t = threadIdx.x;
    f32x4 v = *(const f32x4*)(src + t * 4);
    u16x4 o = {f2bf(v.x), f2bf(v.y), f2bf(v.z), f2bf(v.w)};
    *(u16x4*)(dst + t * 4) = o;
}

// ---------------- 128x128 MFMA GEMM: C[M][N] = A[M][K] * B[N][K]^T (+bias) ----------------
__global__ __launch_bounds__(256) void gemm_bt_kernel(const u16* __restrict__ A,
                                                      const u16* __restrict__ B,
                                                      float* __restrict__ C,
                                                      const float* __restrict__ bias,
                                                      int M, int N, int K) {
    int m0 = blockIdx.x * 128;
    int n0 = blockIdx.y * 128;
    __shared__ alignas(16) u16 As[128][40];
    __shared__ alignas(16) u16 Bs[128][40];
    int t = threadIdx.x;
    int lane = t & 63, wave = t >> 6;
    int wr = wave >> 1, wc = wave & 1;
    int l15 = lane & 15, l4 = lane >> 4;

    f32x4 acc[4][4];
    f32x4 zv = {0.f, 0.f, 0.f, 0.f};
    for (int mi = 0; mi < 4; ++mi)
        for (int ni = 0; ni < 4; ++ni) acc[mi][ni] = zv;

    for (int k0 = 0; k0 < K; k0 += 32) {
        for (int s = 0; s < 2; ++s) {
            int task = t + s * 256;
            int row = task >> 2, kof = (task & 3) * 8;
            u16x8 av = *(const u16x8*)(A + (size_t)(m0 + row) * K + k0 + kof);
            *(u16x8*)(&As[row][kof]) = av;
            int brow = n0 + row;
            u16x8 bv = {0, 0, 0, 0, 0, 0, 0, 0};
            if (brow < N) bv = *(const u16x8*)(B + (size_t)brow * K + k0 + kof);
            *(u16x8*)(&Bs[row][kof]) = bv;
        }
        __syncthreads();
        bf16x8 af[4], bfr[4];
        for (int mi = 0; mi < 4; ++mi)
            af[mi] = __builtin_bit_cast(bf16x8, *(const u16x8*)(&As[wr * 64 + mi * 16 + l15][l4 * 8]));
        for (int ni = 0; ni < 4; ++ni)
            bfr[ni] = __builtin_bit_cast(bf16x8, *(const u16x8*)(&Bs[wc * 64 + ni * 16 + l15][l4 * 8]));
        for (int mi = 0; mi < 4; ++mi)
            for (int ni = 0; ni < 4; ++ni)
                acc[mi][ni] = __builtin_amdgcn_mfma_f32_16x16x32_bf16(af[mi], bfr[ni], acc[mi][ni], 0, 0, 0);
        __syncthreads();
    }

    for (int mi = 0; mi < 4; ++mi)
        for (int ni = 0; ni < 4; ++ni) {
            int col = n0 + wc * 64 + ni * 16 + l15;
            if (col < N) {
                float bb = bias ? bias[col] : 0.f;
                int rbase = m0 + wr * 64 + mi * 16 + l4 * 4;
                for (int r = 0; r < 4; ++r)
                    C[(size_t)(rbase + r) * N + col] = acc[mi][ni][r] + bb;
            }
        }
}

// ---------------- persistent LSTM recurrence ----------------
// 64 blocks x 256 threads, cooperative. Block owns DPB=16 h-dims -> 64 gate cols.
// w_hh slice in LDS (swizzled), c slice in LDS; per-step grid barrier (slot per step).

__device__ __forceinline__ void grid_sync(unsigned* cnt, int slot) {
    __syncthreads();
    __threadfence();
    if (threadIdx.x == 0) {
        __hip_atomic_fetch_add(&cnt[slot], 1u, __ATOMIC_ACQ_REL, __HIP_MEMORY_SCOPE_AGENT);
        while (__hip_atomic_load(&cnt[slot], __ATOMIC_ACQUIRE, __HIP_MEMORY_SCOPE_AGENT) <
               (unsigned)NB) {
            __builtin_amdgcn_s_sleep(1);
        }
    }
    __syncthreads();
    __threadfence();
}

__global__ __launch_bounds__(256, 1) void lstm_seq_kernel(
    const float* __restrict__ c0, const u16* __restrict__ w_hh_bf,
    const float* __restrict__ gx, const float* __restrict__ Wv, const float* __restrict__ Uv,
    float* __restrict__ hist, u16* __restrict__ hbf, float* __restrict__ c_out,
    float* __restrict__ a_arr, float* __restrict__ b_arr, unsigned* __restrict__ barcnt) {
    __shared__ alignas(16) u16 Bs[64][1024];  // 128KB, XOR-swizzled 16B chunks
    __shared__ float gsm[4][32][16];          // 8KB
    __shared__ float c_sl[32][16];            // 2KB

    int blk = blockIdx.x;
    int d0 = blk * DPB;
    int t = threadIdx.x;
    int lane = t & 63, wave = t >> 6;
    int wm = wave & 1, wn = wave >> 1;
    int l15 = lane & 15, l4 = lane >> 4;

    // stage w_hh slice: LDS row c (= g*16+dl) <- w_hh[g*1024 + d0 + dl][:]
    for (int s = 0; s < 32; ++s) {
        int cid = t + s * 256;  // 0..8191
        int c = cid >> 7;       // 0..63
        int ch = cid & 127;     // 16B chunk
        int g = c >> 4, dl = c & 15;
        u16x8 v = *(const u16x8*)(w_hh_bf + (size_t)(g * HID + d0 + dl) * HID + ch * 8);
        int chs = ch ^ (c & 7);
        *(u16x8*)(&Bs[c][chs * 8]) = v;
    }
    for (int s = t; s < 512; s += 256) {
        int b = s >> 4, dl = s & 15;
        c_sl[b][dl] = c0[b * HID + d0 + dl];
    }
    __syncthreads();

    int cA = wn * 32 + l15;  // gate col, nt=0
    int cB = cA + 16;        // nt=1
    int sw = (cA & 7);       // same for cB
    int gA = cA >> 4, dA = cA & 15;
    int gB = cB >> 4, dB = cB & 15;

    for (int i = 0; i < L_SEQ; ++i) {
        const u16* hb = hbf + (size_t)(i & 1) * (BSZ * HID);
        const u16* aptr = hb + (size_t)(wm * 16 + l15) * HID + l4 * 8;

        // prefetch gx biases for this step (independent of K-loop)
        float gxa[2][4];
#pragma unroll
        for (int r = 0; r < 4; ++r) {
            int m = wm * 16 + l4 * 4 + r;
            size_t rowb = (size_t)(i * BSZ + m) * G4;
            gxa[0][r] = gx[rowb + gA * HID + d0 + dA];
            gxa[1][r] = gx[rowb + gB * HID + d0 + dB];
        }

        f32x4 acc0 = {0.f, 0.f, 0.f, 0.f}, acc1 = {0.f, 0.f, 0.f, 0.f};
#pragma unroll
        for (int kk = 0; kk < 32; ++kk) {
            int k0 = kk * 32;
            bf16x8 af = __builtin_bit_cast(bf16x8, *(const u16x8*)(aptr + k0));
            int ch = (k0 >> 3) + l4;
            bf16x8 b0 = __builtin_bit_cast(bf16x8, *(const u16x8*)(&Bs[cA][(ch ^ sw) * 8]));
            bf16x8 b1 = __builtin_bit_cast(bf16x8, *(const u16x8*)(&Bs[cB][(ch ^ sw) * 8]));
            acc0 = __builtin_amdgcn_mfma_f32_16x16x32_bf16(af, b0, acc0, 0, 0, 0);
            acc1 = __builtin_amdgcn_mfma_f32_16x16x32_bf16(af, b1, acc1, 0, 0, 0);
        }

#pragma unroll
        for (int r = 0; r < 4; ++r) {
            int m = wm * 16 + l4 * 4 + r;
            gsm[gA][m][dA] = acc0[r] + gxa[0][r];
            gsm[gB][m][dB] = acc1[r] + gxa[1][r];
        }
        __syncthreads();

        // cell update: 512 (b,dl) pairs, 2 per thread
        u16* hb_next = hbf + (size_t)((i + 1) & 1) * (BSZ * HID);
#pragma unroll
        for (int s = 0; s < 2; ++s) {
            int b = (t >> 4) + s * 16;
            int dl = t & 15;
            float ig = gsm[0][b][dl], fg = gsm[1][b][dl];
            float gg = gsm[2][b][dl], og = gsm[3][b][dl];
            float si = 1.f / (1.f + expf(-ig));
            float sf = 1.f / (1.f + expf(-fg));
            float so = 1.f / (1.f + expf(-og));
            float cn = sf * c_sl[b][dl] + si * tanhf(gg);
            float hn = so * tanhf(cn);
            c_sl[b][dl] = cn;
            hist[((size_t)i * BSZ + b) * HID + d0 + dl] = hn;
            hb_next[b * HID + d0 + dl] = f2bf(hn);
            float pa = hn * Wv[d0 + dl];
            float pb = hn * Uv[d0 + dl];
#pragma unroll
            for (int mm = 8; mm >= 1; mm >>= 1) {
                pa += __shfl_xor(pa, mm);
                pb += __shfl_xor(pb, mm);
            }
            if (dl == 0) {
                atomicAdd(&a_arr[i * BSZ + b], pa);
                atomicAdd(&b_arr[i * BSZ + b], pb);
            }
        }

        grid_sync(barcnt, i);
    }

    for (int s = t; s < 512; s += 256) {
        int b = s >> 4, dl = s & 15;
        c_out[b * HID + d0 + dl] = c_sl[b][dl];
    }
}

// ---------------- attention: 8 queries per block, one batch per block.y ----------------
__global__ __launch_bounds__(256) void attn_kernel(const float* __restrict__ a_arr,
                                                   const float* __restrict__ b_arr,
                                                   const float* __restrict__ hist,
                                                   u16* __restrict__ ctx_bf) {
    int b = blockIdx.y;
    int i0 = blockIdx.x * 8;
    int t = threadIdx.x;
    __shared__ float att[8][256];
    __shared__ float red[256];

    float bt = b_arr[t * BSZ + b];
    for (int q = 0; q < 8; ++q) {
        int iq = i0 + q;
        att[q][t] = (t <= iq) ? tanhf(a_arr[iq * BSZ + b] + bt) : -INFINITY;
    }
    __syncthreads();
    for (int q = 0; q < 8; ++q) {
        int iq = i0 + q;
        red[t] = att[q][t];
        __syncthreads();
        for (int s = 128; s > 0; s >>= 1) {
            if (t < s) red[t] = fmaxf(red[t], red[t + s]);
            __syncthreads();
        }
        float m = red[0];
        __syncthreads();
        float e = (t <= iq) ? expf(att[q][t] - m) : 0.f;
        red[t] = e;
        __syncthreads();
        for (int s = 128; s > 0; s >>= 1) {
            if (t < s) red[t] += red[t + s];
            __syncthreads();
        }
        float sum = red[0];
        __syncthreads();
        att[q][t] = e / sum;
        __syncthreads();
    }

    int hc = t * 4;
    f32x4 accq[8];
    f32x4 zv = {0.f, 0.f, 0.f, 0.f};
    for (int q = 0; q < 8; ++q) accq[q] = zv;
    int imax = i0 + 7;
    for (int t2 = 0; t2 <= imax; ++t2) {
        f32x4 hv = *(const f32x4*)(hist + ((size_t)t2 * BSZ + b) * HID + hc);
        for (int q = 0; q < 8; ++q) accq[q] += hv * att[q][t2];
    }
    for (int q = 0; q < 8; ++q) {
        size_t row = (size_t)(i0 + q) * BSZ + b;
        u16x4 o = {f2bf(accq[q].x), f2bf(accq[q].y), f2bf(accq[q].z), f2bf(accq[q].w)};
        *(u16x4*)(ctx_bf + row * HID + hc) = o;
    }
}

// ---------------- in-place log_softmax over rows of [8192][10000] ----------------
__global__ __launch_bounds__(256) void logsoftmax_kernel(float* __restrict__ x, int V) {
    int row = blockIdx.x;
    float* p = x + (size_t)row * V;
    __shared__ float red[256];
    int t = threadIdx.x;
    float m = -INFINITY;
    for (int j = t; j < V; j += 256) m = fmaxf(m, p[j]);
    red[t] = m;
    __syncthreads();
    for (int s = 128; s > 0; s >>= 1) {
        if (t < s) red[t] = fmaxf(red[t], red[t + s]);
        __syncthreads();
    }
    m = red[0];
    __syncthreads();
    float sum = 0.f;
    for (int j = t; j < V; j += 256) sum += expf(p[j] - m);
    red[t] = sum;
    __syncthreads();
    for (int s = 128; s > 0; s >>= 1) {
        if (t < s) red[t] += red[t + s];
        __syncthreads();
    }
    float lse = m + logf(red[0]);
    for (int j = t; j < V; j += 256) p[j] = p[j] - lse;
}

extern "C" void kernel_launch(void* const* d_in, const int* in_sizes, int n_in,
                              void* d_out, int out_size, void* d_ws, size_t ws_size,
                              hipStream_t stream) {
    const int* ids = (const int*)d_in[0];
    const float* h0 = (const float*)d_in[1];
    const float* c0 = (const float*)d_in[2];
    const float* emb_w = (const float*)d_in[3];
    const float* w_ih = (const float*)d_in[4];
    const float* w_hh = (const float*)d_in[5];
    const float* dec_w = (const float*)d_in[6];
    const float* dec_b = (const float*)d_in[7];
    const float* Wv = (const float*)d_in[8];
    const float* Uv = (const float*)d_in[9];

    char* p = (char*)d_ws;
    auto alloc = [&](size_t bytes) {
        void* r = (void*)p;
        p += (bytes + 255) & ~(size_t)255;
        return r;
    };
    u16* w_ih_bf = (u16*)alloc((size_t)G4 * NIN * 2);
    u16* w_hh_bf = (u16*)alloc((size_t)G4 * HID * 2);
    u16* dec_w_bf = (u16*)alloc((size_t)VOC * HID * 2);
    u16* A_emb = (u16*)alloc((size_t)MROWS * NIN * 2);
    u16* ctx_bf = (u16*)alloc((size_t)MROWS * HID * 2);
    float* hist = (float*)alloc((size_t)L_SEQ * BSZ * HID * 4);
    float* c_buf = (float*)alloc((size_t)BSZ * HID * 4);
    u16* hbf = (u16*)alloc((size_t)2 * BSZ * HID * 2);
    float* a_arr = (float*)alloc((size_t)L_SEQ * BSZ * 4);
    float* b_arr = (float*)alloc((size_t)L_SEQ * BSZ * 4);
    unsigned* barcnt = (unsigned*)alloc((size_t)L_SEQ * 4);

    float* out = (float*)d_out;
    float* gx = out;  // reuse d_out as gx [8192][4096] f32 until logits overwrite it

    // weight conversions
    cvt_bf16_kernel<<<(G4 * NIN / 4 + 255) / 256, 256, 0, stream>>>(w_ih, w_ih_bf, G4 * NIN / 4);
    cvt_bf16_kernel<<<(G4 * HID / 4 + 255) / 256, 256, 0, stream>>>(w_hh, w_hh_bf, G4 * HID / 4);
    cvt_bf16_kernel<<<(VOC * HID / 4 + 255) / 256, 256, 0, stream>>>(dec_w, dec_w_bf, VOC * HID / 4);
    gather_emb_kernel<<<MROWS, 256, 0, stream>>>(ids, emb_w, A_emb);
    cvt_bf16_kernel<<<(BSZ * HID / 4 + 255) / 256, 256, 0, stream>>>(h0, hbf, BSZ * HID / 4);
    hipMemsetAsync(a_arr, 0, (size_t)2 * L_SEQ * BSZ * 4, stream);  // a_arr + b_arr contiguous
    hipMemsetAsync(barcnt, 0, (size_t)L_SEQ * 4, stream);

    // gx = emb @ w_ih^T
    gemm_bt_kernel<<<dim3(MROWS / 128, G4 / 128), 256, 0, stream>>>(A_emb, w_ih_bf, gx, nullptr,
                                                                    MROWS, G4, NIN);
    // persistent recurrence (cooperative: per-step grid barrier)
    {
        const float* c0a = c0;
        const u16* whha = w_hh_bf;
        const float* gxa = gx;
        const float* Wa = Wv;
        const float* Ua = Uv;
        float* hista = hist;
        u16* hbfa = hbf;
        float* couta = c_buf;
        float* aa = a_arr;
        float* ba = b_arr;
        unsigned* bc = barcnt;
        void* args[] = {&c0a, &whha, &gxa, &Wa, &Ua, &hista, &hbfa, &couta, &aa, &ba, &bc};
        hipLaunchCooperativeKernel((const void*)lstm_seq_kernel, dim3(NB), dim3(256), args, 0,
                                   stream);
    }
    // attention -> ctx (bf16)
    attn_kernel<<<dim3(L_SEQ / 8, BSZ), 256, 0, stream>>>(a_arr, b_arr, hist, ctx_bf);
    // logits = ctx @ dec_w^T + dec_b  (into d_out)
    gemm_bt_kernel<<<dim3(MROWS / 128, (VOC + 127) / 128), 256, 0, stream>>>(ctx_bf, dec_w_bf, out,
                                                                             dec_b, MROWS, VOC, HID);
    // in-place log_softmax
    logsoftmax_kernel<<<MROWS, 256, 0, stream>>>(out, VOC);
    // tail outputs: h = hist[255], c = c_buf
    hipMemcpyAsync(out + (size_t)MROWS * VOC, hist + (size_t)255 * BSZ * HID,
                   (size_t)BSZ * HID * 4, hipMemcpyDeviceToDevice, stream);
    hipMemcpyAsync(out + (size_t)MROWS * VOC + BSZ * HID, c_buf,
                   (size_t)BSZ * HID * 4, hipMemcpyDeviceToDevice, stream);
}

// Round 3
// 3114.581 us; speedup vs baseline: 1.8382x; 1.7174x over previous
//
#include <hip/hip_runtime.h>
#include <math.h>

typedef unsigned short u16;
typedef float f32x4 __attribute__((ext_vector_type(4)));
typedef float f32x2 __attribute__((ext_vector_type(2)));
typedef __bf16 bf16x8 __attribute__((ext_vector_type(8)));
typedef u16 u16x8 __attribute__((ext_vector_type(8)));
typedef u16 u16x4 __attribute__((ext_vector_type(4)));

#define L_SEQ 256
#define BSZ 32
#define HID 1024
#define NIN 1024
#define VOC 10000
#define G4 4096
#define MROWS 8192  // L_SEQ*BSZ
#define NB 64       // persistent blocks
#define DPB 16      // h-dims per block

__device__ __forceinline__ u16 f2bf(float f) {
    unsigned u = __float_as_uint(f);
    unsigned r = u + 0x7FFFu + ((u >> 16) & 1u);
    return (u16)(r >> 16);
}

// ---------------- converters ----------------
__global__ __launch_bounds__(256) void cvt_bf16_kernel(const float* __restrict__ in,
                                                       u16* __restrict__ out, int n4) {
    int idx = blockIdx.x * 256 + threadIdx.x;
    if (idx < n4) {
        f32x4 v = *(const f32x4*)(in + (size_t)idx * 4);
        u16x4 o = {f2bf(v.x), f2bf(v.y), f2bf(v.z), f2bf(v.w)};
        *(u16x4*)(out + (size_t)idx * 4) = o;
    }
}

// gather emb rows -> bf16 A matrix [8192][1024]
__global__ __launch_bounds__(256) void gather_emb_kernel(const int* __restrict__ ids,
                                                         const float* __restrict__ emb_w,
                                                         u16* __restrict__ out) {
    int m = blockIdx.x;
    int id = ids[m];
    const float* src = emb_w + (size_t)id * NIN;
    u16* dst = out + (size_t)m * NIN;
    int t = threadIdx.x;
    f32x4 v = *(const f32x4*)(src + t * 4);
    u16x4 o = {f2bf(v.x), f2bf(v.y), f2bf(v.z), f2bf(v.w)};
    *(u16x4*)(dst + t * 4) = o;
}

// ---------------- 128x128 MFMA GEMM: C[M][N] = A[M][K] * B[N][K]^T (+bias) ----------------
__global__ __launch_bounds__(256) void gemm_bt_kernel(const u16* __restrict__ A,
                                                      const u16* __restrict__ B,
                                                      float* __restrict__ C,
                                                      const float* __restrict__ bias,
                                                      int M, int N, int K) {
    int m0 = blockIdx.x * 128;
    int n0 = blockIdx.y * 128;
    __shared__ alignas(16) u16 As[128][40];
    __shared__ alignas(16) u16 Bs[128][40];
    int t = threadIdx.x;
    int lane = t & 63, wave = t >> 6;
    int wr = wave >> 1, wc = wave & 1;
    int l15 = lane & 15, l4 = lane >> 4;

    f32x4 acc[4][4];
    f32x4 zv = {0.f, 0.f, 0.f, 0.f};
    for (int mi = 0; mi < 4; ++mi)
        for (int ni = 0; ni < 4; ++ni) acc[mi][ni] = zv;

    for (int k0 = 0; k0 < K; k0 += 32) {
        for (int s = 0; s < 2; ++s) {
            int task = t + s * 256;
            int row = task >> 2, kof = (task & 3) * 8;
            u16x8 av = *(const u16x8*)(A + (size_t)(m0 + row) * K + k0 + kof);
            *(u16x8*)(&As[row][kof]) = av;
            int brow = n0 + row;
            u16x8 bv = {0, 0, 0, 0, 0, 0, 0, 0};
            if (brow < N) bv = *(const u16x8*)(B + (size_t)brow * K + k0 + kof);
            *(u16x8*)(&Bs[row][kof]) = bv;
        }
        __syncthreads();
        bf16x8 af[4], bfr[4];
        for (int mi = 0; mi < 4; ++mi)
            af[mi] = __builtin_bit_cast(bf16x8, *(const u16x8*)(&As[wr * 64 + mi * 16 + l15][l4 * 8]));
        for (int ni = 0; ni < 4; ++ni)
            bfr[ni] = __builtin_bit_cast(bf16x8, *(const u16x8*)(&Bs[wc * 64 + ni * 16 + l15][l4 * 8]));
        for (int mi = 0; mi < 4; ++mi)
            for (int ni = 0; ni < 4; ++ni)
                acc[mi][ni] = __builtin_amdgcn_mfma_f32_16x16x32_bf16(af[mi], bfr[ni], acc[mi][ni], 0, 0, 0);
        __syncthreads();
    }

    for (int mi = 0; mi < 4; ++mi)
        for (int ni = 0; ni < 4; ++ni) {
            int col = n0 + wc * 64 + ni * 16 + l15;
            if (col < N) {
                float bb = bias ? bias[col] : 0.f;
                int rbase = m0 + wr * 64 + mi * 16 + l4 * 4;
                for (int r = 0; r < 4; ++r)
                    C[(size_t)(rbase + r) * N + col] = acc[mi][ni][r] + bb;
            }
        }
}

// ---------------- persistent LSTM recurrence (fence-free flag protocol) ----------------
// 64 blocks x 256 threads, cooperative. Block owns DPB=16 h-dims -> 64 gate cols.
// h history is a 257-deep buffer; step i reads hb_hist[i], writes hb_hist[i+1] via
// write-through (agent-scope relaxed atomic) stores, then sets flags[i+1][blk].
// Consumers poll flags (relaxed atomic loads) and read A-fragments with sc0|sc1 loads.
// No fences, no contended atomics anywhere in the loop.

__global__ __launch_bounds__(256, 1) void lstm_seq_kernel(
    const float* __restrict__ c0, const u16* __restrict__ w_hh_bf,
    const float* __restrict__ gx, const float* __restrict__ Wv, const float* __restrict__ Uv,
    float* __restrict__ hist, u16* __restrict__ hb_hist, float* __restrict__ c_out,
    float* __restrict__ part_ab, unsigned* __restrict__ flags) {
    __shared__ alignas(16) u16 Bs[64][1024];  // 128KB w_hh slice, XOR-swizzled 16B chunks
    __shared__ float gsm[4][32][16];          // gates
    __shared__ float c_sl[32][16];            // resident cell state

    int blk = blockIdx.x;
    int d0 = blk * DPB;
    int t = threadIdx.x;
    int lane = t & 63, wave = t >> 6;
    int wm = wave & 1, wn = wave >> 1;
    int l15 = lane & 15, l4 = lane >> 4;

    // stage w_hh slice: LDS row c (= g*16+dl) <- w_hh[g*1024 + d0 + dl][:]
    for (int s = 0; s < 32; ++s) {
        int cid = t + s * 256;  // 0..8191
        int c = cid >> 7;       // 0..63
        int ch = cid & 127;     // 16B chunk
        int g = c >> 4, dl = c & 15;
        u16x8 v = *(const u16x8*)(w_hh_bf + (size_t)(g * HID + d0 + dl) * HID + ch * 8);
        int chs = ch ^ (c & 7);
        *(u16x8*)(&Bs[c][chs * 8]) = v;
    }
    for (int s = t; s < 512; s += 256) {
        int b = s >> 4, dl = s & 15;
        c_sl[b][dl] = c0[b * HID + d0 + dl];
    }
    __syncthreads();

    int cA = wn * 32 + l15;  // gate col, nt=0
    int cB = cA + 16;        // nt=1
    int sw = cA & 7;
    int gA = cA >> 4, dA = cA & 15;
    int gB = cB >> 4, dB = cB & 15;

    int bb = t >> 3;      // cell-update batch index
    int pr = t & 7;       // dl-pair index
    int dl0 = pr * 2;

    for (int i = 0; i < L_SEQ; ++i) {
        if (i > 0) {
            const unsigned* f = &flags[(size_t)i * NB];
            while (true) {
                unsigned v = __hip_atomic_load(&f[lane], __ATOMIC_RELAXED,
                                               __HIP_MEMORY_SCOPE_AGENT);
                if (__ballot(v != 0) == ~0ull) break;
                __builtin_amdgcn_s_sleep(1);
            }
        }
        asm volatile("" ::: "memory");

        const u16* hb = hb_hist + (size_t)i * (BSZ * HID);
        const u16* aptr = hb + (size_t)(wm * 16 + l15) * HID + l4 * 8;

        // gx gate-bias loads (plain, L2-cached, read-only)
        float gxa[2][4];
#pragma unroll
        for (int r = 0; r < 4; ++r) {
            int m = wm * 16 + l4 * 4 + r;
            size_t rowb = (size_t)(i * BSZ + m) * G4;
            gxa[0][r] = gx[rowb + gA * HID + d0 + dA];
            gxa[1][r] = gx[rowb + gB * HID + d0 + dB];
        }

        // issue all 32 A-fragment loads (bypass L1/L2), then wait once
        u16x8 afr[32];
#pragma unroll
        for (int kk = 0; kk < 32; ++kk) {
            asm volatile("global_load_dwordx4 %0, %1, off offset:%c2 sc0 sc1"
                         : "=v"(afr[kk])
                         : "v"(aptr), "n"(kk * 64));
        }
        asm volatile("s_waitcnt vmcnt(0)" ::: "memory");
        __builtin_amdgcn_sched_barrier(0);

        f32x4 acc0 = {0.f, 0.f, 0.f, 0.f}, acc1 = {0.f, 0.f, 0.f, 0.f};
#pragma unroll
        for (int kk = 0; kk < 32; ++kk) {
            bf16x8 af = __builtin_bit_cast(bf16x8, afr[kk]);
            int ch = kk * 4 + l4;
            bf16x8 b0 = __builtin_bit_cast(bf16x8, *(const u16x8*)(&Bs[cA][(ch ^ sw) * 8]));
            bf16x8 b1 = __builtin_bit_cast(bf16x8, *(const u16x8*)(&Bs[cB][(ch ^ sw) * 8]));
            acc0 = __builtin_amdgcn_mfma_f32_16x16x32_bf16(af, b0, acc0, 0, 0, 0);
            acc1 = __builtin_amdgcn_mfma_f32_16x16x32_bf16(af, b1, acc1, 0, 0, 0);
        }

#pragma unroll
        for (int r = 0; r < 4; ++r) {
            int m = wm * 16 + l4 * 4 + r;
            gsm[gA][m][dA] = acc0[r] + gxa[0][r];
            gsm[gB][m][dB] = acc1[r] + gxa[1][r];
        }
        __syncthreads();

        // cell update: thread handles (bb, dl0) and (bb, dl0+1)
        u16* hb_next = hb_hist + (size_t)(i + 1) * (BSZ * HID);
        float hn01[2];
#pragma unroll
        for (int q = 0; q < 2; ++q) {
            int dl = dl0 + q;
            float ig = gsm[0][bb][dl], fg = gsm[1][bb][dl];
            float gg = gsm[2][bb][dl], og = gsm[3][bb][dl];
            float si = 1.f / (1.f + expf(-ig));
            float sf = 1.f / (1.f + expf(-fg));
            float so = 1.f / (1.f + expf(-og));
            float cn = sf * c_sl[bb][dl] + si * tanhf(gg);
            float hn = so * tanhf(cn);
            c_sl[bb][dl] = cn;
            hn01[q] = hn;
        }
        f32x2 hv = {hn01[0], hn01[1]};
        *(f32x2*)(hist + ((size_t)i * BSZ + bb) * HID + d0 + dl0) = hv;
        unsigned pk = (unsigned)f2bf(hn01[0]) | ((unsigned)f2bf(hn01[1]) << 16);
        __hip_atomic_store((unsigned*)(hb_next + bb * HID + d0 + dl0), pk,
                           __ATOMIC_RELAXED, __HIP_MEMORY_SCOPE_AGENT);
        // a/b partials: reduce over the 8-lane dl-group, one plain store per (i,blk,b)
        float pa = hn01[0] * Wv[d0 + dl0] + hn01[1] * Wv[d0 + dl0 + 1];
        float pb = hn01[0] * Uv[d0 + dl0] + hn01[1] * Uv[d0 + dl0 + 1];
        pa += __shfl_xor(pa, 1); pb += __shfl_xor(pb, 1);
        pa += __shfl_xor(pa, 2); pb += __shfl_xor(pb, 2);
        pa += __shfl_xor(pa, 4); pb += __shfl_xor(pb, 4);
        if (pr == 0) {
            f32x2 pv = {pa, pb};
            *(f32x2*)(part_ab + (((size_t)i * NB + blk) * BSZ + bb) * 2) = pv;
        }
        asm volatile("s_waitcnt vmcnt(0)" ::: "memory");
        __syncthreads();  // all waves' write-through h stores drained
        if (t == 0)
            __hip_atomic_store(&flags[(size_t)(i + 1) * NB + blk], 1u, __ATOMIC_RELAXED,
                               __HIP_MEMORY_SCOPE_AGENT);
    }

    for (int s = t; s < 512; s += 256) {
        int b2 = s >> 4, dl = s & 15;
        c_out[b2 * HID + d0 + dl] = c_sl[b2][dl];
    }
}

// ---------------- reduce a/b partials: a[i][b] = sum_blk part ----------------
__global__ __launch_bounds__(256) void reduce_ab_kernel(const float* __restrict__ part_ab,
                                                        float* __restrict__ a_arr,
                                                        float* __restrict__ b_arr) {
    int i = blockIdx.x;
    int t = threadIdx.x;
    int b = t & 31, q = t >> 5;
    float sa = 0.f, sb = 0.f;
    for (int j = 0; j < 8; ++j) {
        int blk = q * 8 + j;
        f32x2 v = *(const f32x2*)(part_ab + (((size_t)i * NB + blk) * BSZ + b) * 2);
        sa += v.x;
        sb += v.y;
    }
    __shared__ float ra[8][32], rb[8][32];
    ra[q][b] = sa;
    rb[q][b] = sb;
    __syncthreads();
    if (q == 0) {
        for (int j = 1; j < 8; ++j) { sa += ra[j][b]; sb += rb[j][b]; }
        a_arr[i * BSZ + b] = sa;
        b_arr[i * BSZ + b] = sb;
    }
}

// ---------------- attention: 8 queries per block, one batch per block.y ----------------
__global__ __launch_bounds__(256) void attn_kernel(const float* __restrict__ a_arr,
                                                   const float* __restrict__ b_arr,
                                                   const float* __restrict__ hist,
                                                   u16* __restrict__ ctx_bf) {
    int b = blockIdx.y;
    int i0 = blockIdx.x * 8;
    int t = threadIdx.x;
    __shared__ float att[8][256];
    __shared__ float red[256];

    float bt = b_arr[t * BSZ + b];
    for (int q = 0; q < 8; ++q) {
        int iq = i0 + q;
        att[q][t] = (t <= iq) ? tanhf(a_arr[iq * BSZ + b] + bt) : -INFINITY;
    }
    __syncthreads();
    for (int q = 0; q < 8; ++q) {
        int iq = i0 + q;
        red[t] = att[q][t];
        __syncthreads();
        for (int s = 128; s > 0; s >>= 1) {
            if (t < s) red[t] = fmaxf(red[t], red[t + s]);
            __syncthreads();
        }
        float m = red[0];
        __syncthreads();
        float e = (t <= iq) ? expf(att[q][t] - m) : 0.f;
        red[t] = e;
        __syncthreads();
        for (int s = 128; s > 0; s >>= 1) {
            if (t < s) red[t] += red[t + s];
            __syncthreads();
        }
        float sum = red[0];
        __syncthreads();
        att[q][t] = e / sum;
        __syncthreads();
    }

    int hc = t * 4;
    f32x4 accq[8];
    f32x4 zv = {0.f, 0.f, 0.f, 0.f};
    for (int q = 0; q < 8; ++q) accq[q] = zv;
    int imax = i0 + 7;
    for (int t2 = 0; t2 <= imax; ++t2) {
        f32x4 hv = *(const f32x4*)(hist + ((size_t)t2 * BSZ + b) * HID + hc);
        for (int q = 0; q < 8; ++q) accq[q] += hv * att[q][t2];
    }
    for (int q = 0; q < 8; ++q) {
        size_t row = (size_t)(i0 + q) * BSZ + b;
        u16x4 o = {f2bf(accq[q].x), f2bf(accq[q].y), f2bf(accq[q].z), f2bf(accq[q].w)};
        *(u16x4*)(ctx_bf + row * HID + hc) = o;
    }
}

// ---------------- in-place log_softmax over rows of [8192][10000] ----------------
__global__ __launch_bounds__(256) void logsoftmax_kernel(float* __restrict__ x, int V) {
    int row = blockIdx.x;
    float* p = x + (size_t)row * V;
    __shared__ float red[256];
    int t = threadIdx.x;
    float m = -INFINITY;
    for (int j = t; j < V; j += 256) m = fmaxf(m, p[j]);
    red[t] = m;
    __syncthreads();
    for (int s = 128; s > 0; s >>= 1) {
        if (t < s) red[t] = fmaxf(red[t], red[t + s]);
        __syncthreads();
    }
    m = red[0];
    __syncthreads();
    float sum = 0.f;
    for (int j = t; j < V; j += 256) sum += expf(p[j] - m);
    red[t] = sum;
    __syncthreads();
    for (int s = 128; s > 0; s >>= 1) {
        if (t < s) red[t] += red[t + s];
        __syncthreads();
    }
    float lse = m + logf(red[0]);
    for (int j = t; j < V; j += 256) p[j] = p[j] - lse;
}

extern "C" void kernel_launch(void* const* d_in, const int* in_sizes, int n_in,
                              void* d_out, int out_size, void* d_ws, size_t ws_size,
                              hipStream_t stream) {
    const int* ids = (const int*)d_in[0];
    const float* h0 = (const float*)d_in[1];
    const float* c0 = (const float*)d_in[2];
    const float* emb_w = (const float*)d_in[3];
    const float* w_ih = (const float*)d_in[4];
    const float* w_hh = (const float*)d_in[5];
    const float* dec_w = (const float*)d_in[6];
    const float* dec_b = (const float*)d_in[7];
    const float* Wv = (const float*)d_in[8];
    const float* Uv = (const float*)d_in[9];

    char* p = (char*)d_ws;
    auto alloc = [&](size_t bytes) {
        void* r = (void*)p;
        p += (bytes + 255) & ~(size_t)255;
        return r;
    };
    u16* w_ih_bf = (u16*)alloc((size_t)G4 * NIN * 2);
    u16* w_hh_bf = (u16*)alloc((size_t)G4 * HID * 2);
    u16* dec_w_bf = (u16*)alloc((size_t)VOC * HID * 2);
    // A_emb and hb_hist share a region (A_emb dead after gemm1; hb_hist[0] written after)
    char* shared_region = (char*)alloc((size_t)(L_SEQ + 1) * BSZ * HID * 2);
    u16* A_emb = (u16*)shared_region;
    u16* hb_hist = (u16*)shared_region;
    u16* ctx_bf = (u16*)alloc((size_t)MROWS * HID * 2);
    float* hist = (float*)alloc((size_t)L_SEQ * BSZ * HID * 4);
    float* c_buf = (float*)alloc((size_t)BSZ * HID * 4);
    float* part_ab = (float*)alloc((size_t)L_SEQ * NB * BSZ * 2 * 4);
    float* a_arr = (float*)alloc((size_t)L_SEQ * BSZ * 4);
    float* b_arr = (float*)alloc((size_t)L_SEQ * BSZ * 4);
    unsigned* flags = (unsigned*)alloc((size_t)(L_SEQ + 1) * NB * 4);

    float* out = (float*)d_out;
    float* gx = out;  // reuse d_out as gx [8192][4096] f32 until logits overwrite it

    // weight conversions
    cvt_bf16_kernel<<<(G4 * NIN / 4 + 255) / 256, 256, 0, stream>>>(w_ih, w_ih_bf, G4 * NIN / 4);
    cvt_bf16_kernel<<<(G4 * HID / 4 + 255) / 256, 256, 0, stream>>>(w_hh, w_hh_bf, G4 * HID / 4);
    cvt_bf16_kernel<<<(VOC * HID / 4 + 255) / 256, 256, 0, stream>>>(dec_w, dec_w_bf, VOC * HID / 4);
    gather_emb_kernel<<<MROWS, 256, 0, stream>>>(ids, emb_w, A_emb);
    hipMemsetAsync(flags, 0, (size_t)(L_SEQ + 1) * NB * 4, stream);

    // gx = emb @ w_ih^T  (must precede hb_hist[0] write: region overlay)
    gemm_bt_kernel<<<dim3(MROWS / 128, G4 / 128), 256, 0, stream>>>(A_emb, w_ih_bf, gx, nullptr,
                                                                    MROWS, G4, NIN);
    // h(0) = bf16(h0) into hb_hist[0]
    cvt_bf16_kernel<<<(BSZ * HID / 4 + 255) / 256, 256, 0, stream>>>(h0, hb_hist, BSZ * HID / 4);

    // persistent recurrence (cooperative; fence-free flag protocol)
    {
        const float* c0a = c0;
        const u16* whha = w_hh_bf;
        const float* gxa = gx;
        const float* Wa = Wv;
        const float* Ua = Uv;
        float* hista = hist;
        u16* hba = hb_hist;
        float* couta = c_buf;
        float* pab = part_ab;
        unsigned* fl = flags;
        void* args[] = {&c0a, &whha, &gxa, &Wa, &Ua, &hista, &hba, &couta, &pab, &fl};
        hipLaunchCooperativeKernel((const void*)lstm_seq_kernel, dim3(NB), dim3(256), args, 0,
                                   stream);
    }
    // reduce a/b partials
    reduce_ab_kernel<<<L_SEQ, 256, 0, stream>>>(part_ab, a_arr, b_arr);
    // attention -> ctx (bf16)
    attn_kernel<<<dim3(L_SEQ / 8, BSZ), 256, 0, stream>>>(a_arr, b_arr, hist, ctx_bf);
    // logits = ctx @ dec_w^T + dec_b  (into d_out)
    gemm_bt_kernel<<<dim3(MROWS / 128, (VOC + 127) / 128), 256, 0, stream>>>(ctx_bf, dec_w_bf, out,
                                                                             dec_b, MROWS, VOC, HID);
    // in-place log_softmax
    logsoftmax_kernel<<<MROWS, 256, 0, stream>>>(out, VOC);
    // tail outputs: h = hist[255], c = c_buf
    hipMemcpyAsync(out + (size_t)MROWS * VOC, hist + (size_t)255 * BSZ * HID,
                   (size_t)BSZ * HID * 4, hipMemcpyDeviceToDevice, stream);
    hipMemcpyAsync(out + (size_t)MROWS * VOC + BSZ * HID, c_buf,
                   (size_t)BSZ * HID * 4, hipMemcpyDeviceToDevice, stream);
}

// Round 4
// 2642.362 us; speedup vs baseline: 2.1667x; 1.1787x over previous
//
#include <hip/hip_runtime.h>
#include <math.h>

typedef unsigned short u16;
typedef unsigned u32;
typedef float f32x4 __attribute__((ext_vector_type(4)));
typedef float f32x2 __attribute__((ext_vector_type(2)));
typedef __bf16 bf16x8 __attribute__((ext_vector_type(8)));
typedef u16 u16x8 __attribute__((ext_vector_type(8)));
typedef u16 u16x4 __attribute__((ext_vector_type(4)));
typedef u32 u32x4 __attribute__((ext_vector_type(4)));

#define L_SEQ 256
#define BSZ 32
#define HID 1024
#define NIN 1024
#define VOC 10000
#define G4 4096
#define MROWS 8192  // L_SEQ*BSZ
#define NB 64       // persistent blocks
#define DPB 16      // h-dims per block
#define SENT 0xFFFFFFFFu

__device__ __forceinline__ u16 f2bf(float f) {
    unsigned u = __float_as_uint(f);
    unsigned r = u + 0x7FFFu + ((u >> 16) & 1u);
    return (u16)(r >> 16);
}

__device__ __forceinline__ float fast_sigm(float x) {
    x = fminf(fmaxf(x, -15.f), 15.f);
    return __builtin_amdgcn_rcpf(1.f + __expf(-x));
}
__device__ __forceinline__ float fast_tanh(float x) {
    x = fminf(fmaxf(x, -15.f), 15.f);
    float t = __expf(2.f * x);
    return (t - 1.f) * __builtin_amdgcn_rcpf(t + 1.f);
}

__device__ __forceinline__ unsigned umax4(u16x8 v) {
    u32x4 c = __builtin_bit_cast(u32x4, v);
    unsigned a = c.x > c.y ? c.x : c.y;
    unsigned b = c.z > c.w ? c.z : c.w;
    return a > b ? a : b;
}

// ---------------- converters ----------------
__global__ __launch_bounds__(256) void cvt_bf16_kernel(const float* __restrict__ in,
                                                       u16* __restrict__ out, int n4) {
    int idx = blockIdx.x * 256 + threadIdx.x;
    if (idx < n4) {
        f32x4 v = *(const f32x4*)(in + (size_t)idx * 4);
        u16x4 o = {f2bf(v.x), f2bf(v.y), f2bf(v.z), f2bf(v.w)};
        *(u16x4*)(out + (size_t)idx * 4) = o;
    }
}

// gather emb rows -> bf16 A matrix [8192][1024]
__global__ __launch_bounds__(256) void gather_emb_kernel(const int* __restrict__ ids,
                                                         const float* __restrict__ emb_w,
                                                         u16* __restrict__ out) {
    int m = blockIdx.x;
    int id = ids[m];
    const float* src = emb_w + (size_t)id * NIN;
    u16* dst = out + (size_t)m * NIN;
    int t = threadIdx.x;
    f32x4 v = *(const f32x4*)(src + t * 4);
    u16x4 o = {f2bf(v.x), f2bf(v.y), f2bf(v.z), f2bf(v.w)};
    *(u16x4*)(dst + t * 4) = o;
}

// ---------------- 128x128 MFMA GEMM: C[M][N] = A[M][K] * B[N][K]^T (+bias) ----------------
__global__ __launch_bounds__(256) void gemm_bt_kernel(const u16* __restrict__ A,
                                                      const u16* __restrict__ B,
                                                      float* __restrict__ C,
                                                      const float* __restrict__ bias,
                                                      int M, int N, int K) {
    int m0 = blockIdx.x * 128;
    int n0 = blockIdx.y * 128;
    __shared__ alignas(16) u16 As[128][40];
    __shared__ alignas(16) u16 Bs[128][40];
    int t = threadIdx.x;
    int lane = t & 63, wave = t >> 6;
    int wr = wave >> 1, wc = wave & 1;
    int l15 = lane & 15, l4 = lane >> 4;

    f32x4 acc[4][4];
    f32x4 zv = {0.f, 0.f, 0.f, 0.f};
    for (int mi = 0; mi < 4; ++mi)
        for (int ni = 0; ni < 4; ++ni) acc[mi][ni] = zv;

    for (int k0 = 0; k0 < K; k0 += 32) {
        for (int s = 0; s < 2; ++s) {
            int task = t + s * 256;
            int row = task >> 2, kof = (task & 3) * 8;
            u16x8 av = *(const u16x8*)(A + (size_t)(m0 + row) * K + k0 + kof);
            *(u16x8*)(&As[row][kof]) = av;
            int brow = n0 + row;
            u16x8 bv = {0, 0, 0, 0, 0, 0, 0, 0};
            if (brow < N) bv = *(const u16x8*)(B + (size_t)brow * K + k0 + kof);
            *(u16x8*)(&Bs[row][kof]) = bv;
        }
        __syncthreads();
        bf16x8 af[4], bfr[4];
        for (int mi = 0; mi < 4; ++mi)
            af[mi] = __builtin_bit_cast(bf16x8, *(const u16x8*)(&As[wr * 64 + mi * 16 + l15][l4 * 8]));
        for (int ni = 0; ni < 4; ++ni)
            bfr[ni] = __builtin_bit_cast(bf16x8, *(const u16x8*)(&Bs[wc * 64 + ni * 16 + l15][l4 * 8]));
        for (int mi = 0; mi < 4; ++mi)
            for (int ni = 0; ni < 4; ++ni)
                acc[mi][ni] = __builtin_amdgcn_mfma_f32_16x16x32_bf16(af[mi], bfr[ni], acc[mi][ni], 0, 0, 0);
        __syncthreads();
    }

    for (int mi = 0; mi < 4; ++mi)
        for (int ni = 0; ni < 4; ++ni) {
            int col = n0 + wc * 64 + ni * 16 + l15;
            if (col < N) {
                float bb = bias ? bias[col] : 0.f;
                int rbase = m0 + wr * 64 + mi * 16 + l4 * 4;
                for (int r = 0; r < 4; ++r)
                    C[(size_t)(rbase + r) * N + col] = acc[mi][ni][r] + bb;
            }
        }
}

// ---------------- persistent LSTM recurrence (sentinel data-poll protocol) ----------------
// 64 blocks x 256 threads. Block owns DPB=16 h-dims -> 64 gate cols.
// h history: 257-deep bf16 buffer; slots 1..256 pre-filled with 0xFF sentinel.
// Producers: write-through dword stores of packed h (no drain, no flag).
// Consumers: poll A-fragment chunks directly, re-issuing only sentinel chunks.

__global__ __launch_bounds__(256, 1) void lstm_seq_kernel(
    const float* __restrict__ c0, const u16* __restrict__ w_hh_bf,
    const float* __restrict__ gx, const float* __restrict__ Wv, const float* __restrict__ Uv,
    float* __restrict__ hist, u16* __restrict__ hb_hist, float* __restrict__ c_out,
    float* __restrict__ part_ab) {
    __shared__ alignas(16) u16 Bs[64][1024];  // 128KB w_hh slice, XOR-swizzled 16B chunks
    __shared__ float gsm[4][32][16];
    __shared__ float c_sl[32][16];

    int blk = blockIdx.x;
    int d0 = blk * DPB;
    int t = threadIdx.x;
    int lane = t & 63, wave = t >> 6;
    int wm = wave & 1, wn = wave >> 1;
    int l15 = lane & 15, l4 = lane >> 4;

    // stage w_hh slice: LDS row c (= g*16+dl) <- w_hh[g*1024 + d0 + dl][:]
    for (int s = 0; s < 32; ++s) {
        int cid = t + s * 256;
        int c = cid >> 7;
        int ch = cid & 127;
        int g = c >> 4, dl = c & 15;
        u16x8 v = *(const u16x8*)(w_hh_bf + (size_t)(g * HID + d0 + dl) * HID + ch * 8);
        int chs = ch ^ (c & 7);
        *(u16x8*)(&Bs[c][chs * 8]) = v;
    }
    for (int s = t; s < 512; s += 256) {
        int b = s >> 4, dl = s & 15;
        c_sl[b][dl] = c0[b * HID + d0 + dl];
    }
    __syncthreads();

    int cA = wn * 32 + l15;  // gate col, nt=0
    int cB = cA + 16;        // nt=1
    int sw = cA & 7;
    int gA = cA >> 4, dA = cA & 15;
    int gB = cB >> 4, dB = cB & 15;

    int bb = t >> 3;  // cell-update batch index
    int pr = t & 7;   // dl-pair index
    int dl0 = pr * 2;

    for (int i = 0; i < L_SEQ; ++i) {
        const u16* hb = hb_hist + (size_t)i * (BSZ * HID);
        const u16* aptr = hb + (size_t)(wm * 16 + l15) * HID + l4 * 8;

        // gx gate biases (plain loads; complete under the first poll round)
        float gxa[2][4];
#pragma unroll
        for (int r = 0; r < 4; ++r) {
            int m = wm * 16 + l4 * 4 + r;
            size_t rowb = (size_t)(i * BSZ + m) * G4;
            gxa[0][r] = gx[rowb + gA * HID + d0 + dA];
            gxa[1][r] = gx[rowb + gB * HID + d0 + dB];
        }

        // data-poll: load A-fragments, re-issue chunks still holding the sentinel
        u16x8 afr[32];
        unsigned needmask = 0xFFFFFFFFu;
        do {
#pragma unroll
            for (int kk = 0; kk < 32; ++kk)
                if (needmask & (1u << kk))
                    asm volatile("global_load_dwordx4 %0, %1, off offset:%c2 sc0 sc1"
                                 : "=v"(afr[kk])
                                 : "v"(aptr), "n"(kk * 64));
            asm volatile("s_waitcnt vmcnt(0)" ::: "memory");
            __builtin_amdgcn_sched_barrier(0);
            unsigned nm = 0;
#pragma unroll
            for (int kk = 0; kk < 32; ++kk)
                if (needmask & (1u << kk)) {
                    if (__ballot(umax4(afr[kk]) == SENT)) nm |= (1u << kk);
                }
            needmask = nm;
            if (needmask) __builtin_amdgcn_s_sleep(1);
        } while (needmask);
        __builtin_amdgcn_sched_barrier(0);

        f32x4 acc0 = {0.f, 0.f, 0.f, 0.f}, acc1 = {0.f, 0.f, 0.f, 0.f};
#pragma unroll
        for (int kk = 0; kk < 32; ++kk) {
            bf16x8 af = __builtin_bit_cast(bf16x8, afr[kk]);
            int ch = kk * 4 + l4;
            bf16x8 b0 = __builtin_bit_cast(bf16x8, *(const u16x8*)(&Bs[cA][(ch ^ sw) * 8]));
            bf16x8 b1 = __builtin_bit_cast(bf16x8, *(const u16x8*)(&Bs[cB][(ch ^ sw) * 8]));
            acc0 = __builtin_amdgcn_mfma_f32_16x16x32_bf16(af, b0, acc0, 0, 0, 0);
            acc1 = __builtin_amdgcn_mfma_f32_16x16x32_bf16(af, b1, acc1, 0, 0, 0);
        }

#pragma unroll
        for (int r = 0; r < 4; ++r) {
            int m = wm * 16 + l4 * 4 + r;
            gsm[gA][m][dA] = acc0[r] + gxa[0][r];
            gsm[gB][m][dB] = acc1[r] + gxa[1][r];
        }
        __syncthreads();

        // cell update: thread handles (bb, dl0) and (bb, dl0+1); publish h ASAP
        u16* hb_next = hb_hist + (size_t)(i + 1) * (BSZ * HID);
        float hn01[2];
#pragma unroll
        for (int q = 0; q < 2; ++q) {
            int dl = dl0 + q;
            float ig = gsm[0][bb][dl], fg = gsm[1][bb][dl];
            float gg = gsm[2][bb][dl], og = gsm[3][bb][dl];
            float cn = fast_sigm(fg) * c_sl[bb][dl] + fast_sigm(ig) * fast_tanh(gg);
            float hn = fast_sigm(og) * fast_tanh(cn);
            c_sl[bb][dl] = cn;
            hn01[q] = hn;
        }
        unsigned pk = (unsigned)f2bf(hn01[0]) | ((unsigned)f2bf(hn01[1]) << 16);
        __hip_atomic_store((unsigned*)(hb_next + bb * HID + d0 + dl0), pk,
                           __ATOMIC_RELAXED, __HIP_MEMORY_SCOPE_AGENT);
        // off-critical-path outputs
        f32x2 hv = {hn01[0], hn01[1]};
        *(f32x2*)(hist + ((size_t)i * BSZ + bb) * HID + d0 + dl0) = hv;
        float pa = hn01[0] * Wv[d0 + dl0] + hn01[1] * Wv[d0 + dl0 + 1];
        float pb = hn01[0] * Uv[d0 + dl0] + hn01[1] * Uv[d0 + dl0 + 1];
        pa += __shfl_xor(pa, 1); pb += __shfl_xor(pb, 1);
        pa += __shfl_xor(pa, 2); pb += __shfl_xor(pb, 2);
        pa += __shfl_xor(pa, 4); pb += __shfl_xor(pb, 4);
        if (pr == 0) {
            f32x2 pv = {pa, pb};
            *(f32x2*)(part_ab + (((size_t)i * NB + blk) * BSZ + bb) * 2) = pv;
        }
        // no drain, no flag: consumers poll the data itself
    }

    for (int s = t; s < 512; s += 256) {
        int b2 = s >> 4, dl = s & 15;
        c_out[b2 * HID + d0 + dl] = c_sl[b2][dl];
    }
}

// ---------------- reduce a/b partials: a[i][b] = sum_blk part ----------------
__global__ __launch_bounds__(256) void reduce_ab_kernel(const float* __restrict__ part_ab,
                                                        float* __restrict__ a_arr,
                                                        float* __restrict__ b_arr) {
    int i = blockIdx.x;
    int t = threadIdx.x;
    int b = t & 31, q = t >> 5;
    float sa = 0.f, sb = 0.f;
    for (int j = 0; j < 8; ++j) {
        int blk = q * 8 + j;
        f32x2 v = *(const f32x2*)(part_ab + (((size_t)i * NB + blk) * BSZ + b) * 2);
        sa += v.x;
        sb += v.y;
    }
    __shared__ float ra[8][32], rb[8][32];
    ra[q][b] = sa;
    rb[q][b] = sb;
    __syncthreads();
    if (q == 0) {
        for (int j = 1; j < 8; ++j) { sa += ra[j][b]; sb += rb[j][b]; }
        a_arr[i * BSZ + b] = sa;
        b_arr[i * BSZ + b] = sb;
    }
}

// ---------------- attention: 8 queries per block, one batch per block.y ----------------
__global__ __launch_bounds__(256) void attn_kernel(const float* __restrict__ a_arr,
                                                   const float* __restrict__ b_arr,
                                                   const float* __restrict__ hist,
                                                   u16* __restrict__ ctx_bf) {
    int b = blockIdx.y;
    int i0 = blockIdx.x * 8;
    int t = threadIdx.x;
    __shared__ float att[8][256];
    __shared__ float red[256];

    float bt = b_arr[t * BSZ + b];
    for (int q = 0; q < 8; ++q) {
        int iq = i0 + q;
        att[q][t] = (t <= iq) ? tanhf(a_arr[iq * BSZ + b] + bt) : -INFINITY;
    }
    __syncthreads();
    for (int q = 0; q < 8; ++q) {
        int iq = i0 + q;
        red[t] = att[q][t];
        __syncthreads();
        for (int s = 128; s > 0; s >>= 1) {
            if (t < s) red[t] = fmaxf(red[t], red[t + s]);
            __syncthreads();
        }
        float m = red[0];
        __syncthreads();
        float e = (t <= iq) ? expf(att[q][t] - m) : 0.f;
        red[t] = e;
        __syncthreads();
        for (int s = 128; s > 0; s >>= 1) {
            if (t < s) red[t] += red[t + s];
            __syncthreads();
        }
        float sum = red[0];
        __syncthreads();
        att[q][t] = e / sum;
        __syncthreads();
    }

    int hc = t * 4;
    f32x4 accq[8];
    f32x4 zv = {0.f, 0.f, 0.f, 0.f};
    for (int q = 0; q < 8; ++q) accq[q] = zv;
    int imax = i0 + 7;
    for (int t2 = 0; t2 <= imax; ++t2) {
        f32x4 hv = *(const f32x4*)(hist + ((size_t)t2 * BSZ + b) * HID + hc);
        for (int q = 0; q < 8; ++q) accq[q] += hv * att[q][t2];
    }
    for (int q = 0; q < 8; ++q) {
        size_t row = (size_t)(i0 + q) * BSZ + b;
        u16x4 o = {f2bf(accq[q].x), f2bf(accq[q].y), f2bf(accq[q].z), f2bf(accq[q].w)};
        *(u16x4*)(ctx_bf + row * HID + hc) = o;
    }
}

// ---------------- in-place log_softmax over rows of [8192][10000], register-cached ----------------
__global__ __launch_bounds__(256) void logsoftmax_kernel(float* __restrict__ x, int V) {
    int row = blockIdx.x;
    float* p = x + (size_t)row * V;
    __shared__ float red[256];
    int t = threadIdx.x;
    float frag[40];
    float m = -INFINITY;
#pragma unroll
    for (int k = 0; k < 40; ++k) {
        int j = t + k * 256;
        if (j < VOC) {
            frag[k] = p[j];
            m = fmaxf(m, frag[k]);
        }
    }
    red[t] = m;
    __syncthreads();
    for (int s = 128; s > 0; s >>= 1) {
        if (t < s) red[t] = fmaxf(red[t], red[t + s]);
        __syncthreads();
    }
    m = red[0];
    __syncthreads();
    float sum = 0.f;
#pragma unroll
    for (int k = 0; k < 40; ++k) {
        int j = t + k * 256;
        if (j < VOC) sum += __expf(frag[k] - m);
    }
    red[t] = sum;
    __syncthreads();
    for (int s = 128; s > 0; s >>= 1) {
        if (t < s) red[t] += red[t + s];
        __syncthreads();
    }
    float lse = m + logf(red[0]);
#pragma unroll
    for (int k = 0; k < 40; ++k) {
        int j = t + k * 256;
        if (j < VOC) p[j] = frag[k] - lse;
    }
}

extern "C" void kernel_launch(void* const* d_in, const int* in_sizes, int n_in,
                              void* d_out, int out_size, void* d_ws, size_t ws_size,
                              hipStream_t stream) {
    const int* ids = (const int*)d_in[0];
    const float* h0 = (const float*)d_in[1];
    const float* c0 = (const float*)d_in[2];
    const float* emb_w = (const float*)d_in[3];
    const float* w_ih = (const float*)d_in[4];
    const float* w_hh = (const float*)d_in[5];
    const float* dec_w = (const float*)d_in[6];
    const float* dec_b = (const float*)d_in[7];
    const float* Wv = (const float*)d_in[8];
    const float* Uv = (const float*)d_in[9];

    char* p = (char*)d_ws;
    auto alloc = [&](size_t bytes) {
        void* r = (void*)p;
        p += (bytes + 255) & ~(size_t)255;
        return r;
    };
    u16* w_ih_bf = (u16*)alloc((size_t)G4 * NIN * 2);
    u16* w_hh_bf = (u16*)alloc((size_t)G4 * HID * 2);
    u16* dec_w_bf = (u16*)alloc((size_t)VOC * HID * 2);
    // A_emb and hb_hist share a region (A_emb dead after gemm1)
    char* shared_region = (char*)alloc((size_t)(L_SEQ + 1) * BSZ * HID * 2);
    u16* A_emb = (u16*)shared_region;
    u16* hb_hist = (u16*)shared_region;
    u16* ctx_bf = (u16*)alloc((size_t)MROWS * HID * 2);
    float* hist = (float*)alloc((size_t)L_SEQ * BSZ * HID * 4);
    float* c_buf = (float*)alloc((size_t)BSZ * HID * 4);
    float* part_ab = (float*)alloc((size_t)L_SEQ * NB * BSZ * 2 * 4);
    float* a_arr = (float*)alloc((size_t)L_SEQ * BSZ * 4);
    float* b_arr = (float*)alloc((size_t)L_SEQ * BSZ * 4);

    float* out = (float*)d_out;
    float* gx = out;  // reuse d_out as gx [8192][4096] f32 until logits overwrite it

    // weight conversions
    cvt_bf16_kernel<<<(G4 * NIN / 4 + 255) / 256, 256, 0, stream>>>(w_ih, w_ih_bf, G4 * NIN / 4);
    cvt_bf16_kernel<<<(G4 * HID / 4 + 255) / 256, 256, 0, stream>>>(w_hh, w_hh_bf, G4 * HID / 4);
    cvt_bf16_kernel<<<(VOC * HID / 4 + 255) / 256, 256, 0, stream>>>(dec_w, dec_w_bf, VOC * HID / 4);
    gather_emb_kernel<<<MROWS, 256, 0, stream>>>(ids, emb_w, A_emb);

    // gx = emb @ w_ih^T  (must precede hb_hist overlay writes)
    gemm_bt_kernel<<<dim3(MROWS / 128, G4 / 128), 256, 0, stream>>>(A_emb, w_ih_bf, gx, nullptr,
                                                                    MROWS, G4, NIN);
    // sentinel-fill slots 1..256, then h(0) = bf16(h0) into slot 0
    hipMemsetAsync(hb_hist + (size_t)BSZ * HID, 0xFF, (size_t)L_SEQ * BSZ * HID * 2, stream);
    cvt_bf16_kernel<<<(BSZ * HID / 4 + 255) / 256, 256, 0, stream>>>(h0, hb_hist, BSZ * HID / 4);

    // persistent recurrence (sentinel data-poll; no grid barrier, no flags)
    {
        const float* c0a = c0;
        const u16* whha = w_hh_bf;
        const float* gxa = gx;
        const float* Wa = Wv;
        const float* Ua = Uv;
        float* hista = hist;
        u16* hba = hb_hist;
        float* couta = c_buf;
        float* pab = part_ab;
        void* args[] = {&c0a, &whha, &gxa, &Wa, &Ua, &hista, &hba, &couta, &pab};
        hipLaunchCooperativeKernel((const void*)lstm_seq_kernel, dim3(NB), dim3(256), args, 0,
                                   stream);
    }
    // reduce a/b partials
    reduce_ab_kernel<<<L_SEQ, 256, 0, stream>>>(part_ab, a_arr, b_arr);
    // attention -> ctx (bf16)
    attn_kernel<<<dim3(L_SEQ / 8, BSZ), 256, 0, stream>>>(a_arr, b_arr, hist, ctx_bf);
    // logits = ctx @ dec_w^T + dec_b  (into d_out)
    gemm_bt_kernel<<<dim3(MROWS / 128, (VOC + 127) / 128), 256, 0, stream>>>(ctx_bf, dec_w_bf, out,
                                                                             dec_b, MROWS, VOC, HID);
    // in-place log_softmax
    logsoftmax_kernel<<<MROWS, 256, 0, stream>>>(out, VOC);
    // tail outputs: h = hist[255], c = c_buf
    hipMemcpyAsync(out + (size_t)MROWS * VOC, hist + (size_t)255 * BSZ * HID,
                   (size_t)BSZ * HID * 4, hipMemcpyDeviceToDevice, stream);
    hipMemcpyAsync(out + (size_t)MROWS * VOC + BSZ * HID, c_buf,
                   (size_t)BSZ * HID * 4, hipMemcpyDeviceToDevice, stream);
}

// Round 8
// 2587.132 us; speedup vs baseline: 2.2129x; 1.0213x over previous
//
#include <hip/hip_runtime.h>
#include <math.h>

typedef unsigned short u16;
typedef unsigned u32;
typedef float f32x4 __attribute__((ext_vector_type(4)));
typedef float f32x2 __attribute__((ext_vector_type(2)));
typedef __bf16 bf16x8 __attribute__((ext_vector_type(8)));
typedef u16 u16x8 __attribute__((ext_vector_type(8)));
typedef u16 u16x4 __attribute__((ext_vector_type(4)));
typedef u32 u32x4 __attribute__((ext_vector_type(4)));

#define L_SEQ 256
#define BSZ 32
#define HID 1024
#define NIN 1024
#define VOC 10000
#define G4 4096
#define MROWS 8192
#define NB 64    // recurrence blocks
#define DPB 16   // h-dims per block
#define SENT 0xFFFFFFFFu

__device__ __forceinline__ u16 f2bf(float f) {
    unsigned u = __float_as_uint(f);
    unsigned r = u + 0x7FFFu + ((u >> 16) & 1u);
    return (u16)(r >> 16);
}
#define BF2F(x) __builtin_bit_cast(float, (u32)((u16)(x)) << 16)

__device__ __forceinline__ float fast_sigm(float x) {
    x = fminf(fmaxf(x, -15.f), 15.f);
    return __builtin_amdgcn_rcpf(1.f + __expf(-x));
}
__device__ __forceinline__ float fast_tanh(float x) {
    x = fminf(fmaxf(x, -15.f), 15.f);
    float t = __expf(2.f * x);
    return (t - 1.f) * __builtin_amdgcn_rcpf(t + 1.f);
}
__device__ __forceinline__ unsigned umax4(u16x8 v) {
    u32x4 c = __builtin_bit_cast(u32x4, v);
    unsigned a = c.x > c.y ? c.x : c.y;
    unsigned b = c.z > c.w ? c.z : c.w;
    return a > b ? a : b;
}

// ---------------- converters ----------------
__global__ __launch_bounds__(256) void cvt_bf16_kernel(const float* __restrict__ in,
                                                       u16* __restrict__ out, int n4) {
    int idx = blockIdx.x * 256 + threadIdx.x;
    if (idx < n4) {
        f32x4 v = *(const f32x4*)(in + (size_t)idx * 4);
        u16x4 o = {f2bf(v.x), f2bf(v.y), f2bf(v.z), f2bf(v.w)};
        *(u16x4*)(out + (size_t)idx * 4) = o;
    }
}

__global__ __launch_bounds__(256) void gather_emb_kernel(const int* __restrict__ ids,
                                                         const float* __restrict__ emb_w,
                                                         u16* __restrict__ out) {
    int m = blockIdx.x;
    int id = ids[m];
    const float* src = emb_w + (size_t)id * NIN;
    u16* dst = out + (size_t)m * NIN;
    int t = threadIdx.x;
    f32x4 v = *(const f32x4*)(src + t * 4);
    u16x4 o = {f2bf(v.x), f2bf(v.y), f2bf(v.z), f2bf(v.w)};
    *(u16x4*)(dst + t * 4) = o;
}

// ---------------- gemm1: gx = emb @ w_ih^T, transposed layout ----------------
// gxT index: (((dblk*L_SEQ + i)*4 + g)*16 + dl)*32 + b   (f32)
__global__ __launch_bounds__(256) void gemm_gxT_kernel(const u16* __restrict__ A,
                                                       const u16* __restrict__ B,
                                                       float* __restrict__ gxT) {
    int m0 = blockIdx.x * 128;
    int n0 = blockIdx.y * 128;
    __shared__ alignas(16) u16 As[128][40];
    __shared__ alignas(16) u16 Bs[128][40];
    int t = threadIdx.x;
    int lane = t & 63, wave = t >> 6;
    int wr = wave >> 1, wc = wave & 1;
    int l15 = lane & 15, l4 = lane >> 4;

    f32x4 acc[4][4];
    f32x4 zv = {0.f, 0.f, 0.f, 0.f};
    for (int mi = 0; mi < 4; ++mi)
        for (int ni = 0; ni < 4; ++ni) acc[mi][ni] = zv;

    for (int k0 = 0; k0 < NIN; k0 += 32) {
        for (int s = 0; s < 2; ++s) {
            int task = t + s * 256;
            int row = task >> 2, kof = (task & 3) * 8;
            *(u16x8*)(&As[row][kof]) = *(const u16x8*)(A + (size_t)(m0 + row) * NIN + k0 + kof);
            *(u16x8*)(&Bs[row][kof]) = *(const u16x8*)(B + (size_t)(n0 + row) * NIN + k0 + kof);
        }
        __syncthreads();
        bf16x8 af[4], bfr[4];
        for (int mi = 0; mi < 4; ++mi)
            af[mi] = __builtin_bit_cast(bf16x8, *(const u16x8*)(&As[wr * 64 + mi * 16 + l15][l4 * 8]));
        for (int ni = 0; ni < 4; ++ni)
            bfr[ni] = __builtin_bit_cast(bf16x8, *(const u16x8*)(&Bs[wc * 64 + ni * 16 + l15][l4 * 8]));
        for (int mi = 0; mi < 4; ++mi)
            for (int ni = 0; ni < 4; ++ni)
                acc[mi][ni] = __builtin_amdgcn_mfma_f32_16x16x32_bf16(af[mi], bfr[ni], acc[mi][ni], 0, 0, 0);
        __syncthreads();
    }
    for (int mi = 0; mi < 4; ++mi)
        for (int ni = 0; ni < 4; ++ni) {
            int n = n0 + wc * 64 + ni * 16 + l15;
            int g = n >> 10, dd = n & 1023;
            int dblk = dd >> 4, dl = dd & 15;
            int mbase = m0 + wr * 64 + mi * 16 + l4 * 4;
            int i = mbase >> 5, bb = mbase & 31;
            size_t idx = ((((size_t)dblk * L_SEQ + i) * 4 + g) * 16 + dl) * 32 + bb;
            *(f32x4*)(&gxT[idx]) = acc[mi][ni];
        }
}

// ---------------- decoder GEMM: C[M][N] = A[M][K] * B[N][K]^T + bias ----------------
__global__ __launch_bounds__(256) void gemm_bt_kernel(const u16* __restrict__ A,
                                                      const u16* __restrict__ B,
                                                      float* __restrict__ C,
                                                      const float* __restrict__ bias,
                                                      int M, int N, int K) {
    int m0 = blockIdx.x * 128;
    int n0 = blockIdx.y * 128;
    __shared__ alignas(16) u16 As[128][40];
    __shared__ alignas(16) u16 Bs[128][40];
    int t = threadIdx.x;
    int lane = t & 63, wave = t >> 6;
    int wr = wave >> 1, wc = wave & 1;
    int l15 = lane & 15, l4 = lane >> 4;

    f32x4 acc[4][4];
    f32x4 zv = {0.f, 0.f, 0.f, 0.f};
    for (int mi = 0; mi < 4; ++mi)
        for (int ni = 0; ni < 4; ++ni) acc[mi][ni] = zv;

    for (int k0 = 0; k0 < K; k0 += 32) {
        for (int s = 0; s < 2; ++s) {
            int task = t + s * 256;
            int row = task >> 2, kof = (task & 3) * 8;
            u16x8 av = *(const u16x8*)(A + (size_t)(m0 + row) * K + k0 + kof);
            *(u16x8*)(&As[row][kof]) = av;
            int brow = n0 + row;
            u16x8 bv = {0, 0, 0, 0, 0, 0, 0, 0};
            if (brow < N) bv = *(const u16x8*)(B + (size_t)brow * K + k0 + kof);
            *(u16x8*)(&Bs[row][kof]) = bv;
        }
        __syncthreads();
        bf16x8 af[4], bfr[4];
        for (int mi = 0; mi < 4; ++mi)
            af[mi] = __builtin_bit_cast(bf16x8, *(const u16x8*)(&As[wr * 64 + mi * 16 + l15][l4 * 8]));
        for (int ni = 0; ni < 4; ++ni)
            bfr[ni] = __builtin_bit_cast(bf16x8, *(const u16x8*)(&Bs[wc * 64 + ni * 16 + l15][l4 * 8]));
        for (int mi = 0; mi < 4; ++mi)
            for (int ni = 0; ni < 4; ++ni)
                acc[mi][ni] = __builtin_amdgcn_mfma_f32_16x16x32_bf16(af[mi], bfr[ni], acc[mi][ni], 0, 0, 0);
        __syncthreads();
    }

    for (int mi = 0; mi < 4; ++mi)
        for (int ni = 0; ni < 4; ++ni) {
            int col = n0 + wc * 64 + ni * 16 + l15;
            if (col < N) {
                float bb = bias ? bias[col] : 0.f;
                int rbase = m0 + wr * 64 + mi * 16 + l4 * 4;
                for (int r = 0; r < 4; ++r)
                    C[(size_t)(rbase + r) * N + col] = acc[mi][ni][r] + bb;
            }
        }
}

// ---------------- persistent LSTM recurrence (r4-exact protocol; coalesced gxT) ----------------
__global__ __launch_bounds__(256, 1) void lstm_seq_kernel(
    const float* __restrict__ c0, const u16* __restrict__ w_hh_bf,
    const float* __restrict__ gxT, const float* __restrict__ Wv, const float* __restrict__ Uv,
    u16* __restrict__ hb_hist, float* __restrict__ out_tail, float* __restrict__ part_ab) {
    __shared__ alignas(16) u16 Bs[64][1024];  // 128KB w_hh slice, XOR-swizzled 16B chunks
    __shared__ float gsm[4][32][16];
    __shared__ float c_sl[32][16];

    int blk = blockIdx.x;
    int d0 = blk * DPB;
    int t = threadIdx.x;
    int lane = t & 63, wave = t >> 6;
    int wm = wave & 1, wn = wave >> 1;
    int l15 = lane & 15, l4 = lane >> 4;

    for (int s = 0; s < 32; ++s) {
        int cid = t + s * 256;
        int c = cid >> 7;
        int ch = cid & 127;
        int g = c >> 4, dl = c & 15;
        u16x8 v = *(const u16x8*)(w_hh_bf + (size_t)(g * HID + d0 + dl) * HID + ch * 8);
        int chs = ch ^ (c & 7);
        *(u16x8*)(&Bs[c][chs * 8]) = v;
    }
    for (int s = t; s < 512; s += 256) {
        int b = s >> 4, dl = s & 15;
        c_sl[b][dl] = c0[b * HID + d0 + dl];
    }
    __syncthreads();

    int cA = wn * 32 + l15;
    int cB = cA + 16;
    int sw = cA & 7;
    int gA = cA >> 4, dA = cA & 15;
    int gB = cB >> 4, dB = cB & 15;

    int bb = t >> 3;
    int pr = t & 7;
    int dl0 = pr * 2;

    const float* gxTb = gxT + (size_t)blk * ((size_t)L_SEQ * 2048) + wm * 16 + l4 * 4;

    for (int i = 0; i < L_SEQ; ++i) {
        const u16* hb = hb_hist + (size_t)i * (BSZ * HID);
        const u16* aptr = hb + (size_t)(wm * 16 + l15) * HID + l4 * 8;

        // coalesced gate-bias loads (f32, exact)
        f32x4 gxa0 = *(const f32x4*)(gxTb + (size_t)i * 2048 + gA * 512 + dA * 32);
        f32x4 gxa1 = *(const f32x4*)(gxTb + (size_t)i * 2048 + gB * 512 + dB * 32);

        // data-poll: load A-fragments, re-issue chunks still holding the sentinel
        u16x8 afr[32];
        unsigned needmask = 0xFFFFFFFFu;
        do {
#pragma unroll
            for (int kk = 0; kk < 32; ++kk)
                if (needmask & (1u << kk))
                    asm volatile("global_load_dwordx4 %0, %1, off offset:%c2 sc0 sc1"
                                 : "=v"(afr[kk])
                                 : "v"(aptr), "n"(kk * 64));
            asm volatile("s_waitcnt vmcnt(0)" ::: "memory");
            __builtin_amdgcn_sched_barrier(0);
            unsigned nm = 0;
#pragma unroll
            for (int kk = 0; kk < 32; ++kk)
                if (needmask & (1u << kk)) {
                    if (__ballot(umax4(afr[kk]) == SENT)) nm |= (1u << kk);
                }
            needmask = nm;
            if (needmask) __builtin_amdgcn_s_sleep(1);
        } while (needmask);
        __builtin_amdgcn_sched_barrier(0);

        f32x4 acc0 = {0.f, 0.f, 0.f, 0.f}, acc1 = {0.f, 0.f, 0.f, 0.f};
#pragma unroll
        for (int kk = 0; kk < 32; ++kk) {
            bf16x8 af = __builtin_bit_cast(bf16x8, afr[kk]);
            int ch = kk * 4 + l4;
            bf16x8 b0 = __builtin_bit_cast(bf16x8, *(const u16x8*)(&Bs[cA][(ch ^ sw) * 8]));
            bf16x8 b1 = __builtin_bit_cast(bf16x8, *(const u16x8*)(&Bs[cB][(ch ^ sw) * 8]));
            acc0 = __builtin_amdgcn_mfma_f32_16x16x32_bf16(af, b0, acc0, 0, 0, 0);
            acc1 = __builtin_amdgcn_mfma_f32_16x16x32_bf16(af, b1, acc1, 0, 0, 0);
        }

#pragma unroll
        for (int r = 0; r < 4; ++r) {
            int m = wm * 16 + l4 * 4 + r;
            gsm[gA][m][dA] = acc0[r] + gxa0[r];
            gsm[gB][m][dB] = acc1[r] + gxa1[r];
        }
        __syncthreads();

        // cell update: thread handles (bb, dl0) and (bb, dl0+1); publish h ASAP
        u16* hb_next = hb_hist + (size_t)(i + 1) * (BSZ * HID);
        float hn01[2];
#pragma unroll
        for (int q = 0; q < 2; ++q) {
            int dl = dl0 + q;
            float ig = gsm[0][bb][dl], fg = gsm[1][bb][dl];
            float gg = gsm[2][bb][dl], og = gsm[3][bb][dl];
            float cn = fast_sigm(fg) * c_sl[bb][dl] + fast_sigm(ig) * fast_tanh(gg);
            float hn = fast_sigm(og) * fast_tanh(cn);
            c_sl[bb][dl] = cn;
            hn01[q] = hn;
        }
        unsigned pk = (unsigned)f2bf(hn01[0]) | ((unsigned)f2bf(hn01[1]) << 16);
        __hip_atomic_store((unsigned*)(hb_next + bb * HID + d0 + dl0), pk,
                           __ATOMIC_RELAXED, __HIP_MEMORY_SCOPE_AGENT);
        if (i == L_SEQ - 1) {
            f32x2 hv = {hn01[0], hn01[1]};
            *(f32x2*)(out_tail + (size_t)bb * HID + d0 + dl0) = hv;
        }
        float pa = hn01[0] * Wv[d0 + dl0] + hn01[1] * Wv[d0 + dl0 + 1];
        float pb = hn01[0] * Uv[d0 + dl0] + hn01[1] * Uv[d0 + dl0 + 1];
        pa += __shfl_xor(pa, 1); pb += __shfl_xor(pb, 1);
        pa += __shfl_xor(pa, 2); pb += __shfl_xor(pb, 2);
        pa += __shfl_xor(pa, 4); pb += __shfl_xor(pb, 4);
        if (pr == 0) {
            f32x2 pv = {pa, pb};
            *(f32x2*)(part_ab + (((size_t)i * NB + blk) * BSZ + bb) * 2) = pv;
        }
    }

    for (int s = t; s < 512; s += 256) {
        int b2 = s >> 4, dl = s & 15;
        out_tail[(size_t)BSZ * HID + b2 * HID + d0 + dl] = c_sl[b2][dl];
    }
}

// ---------------- reduce a/b partials: a[i][b] = sum_blk part ----------------
__global__ __launch_bounds__(256) void reduce_ab_kernel(const float* __restrict__ part_ab,
                                                        float* __restrict__ a_arr,
                                                        float* __restrict__ b_arr) {
    int i = blockIdx.x;
    int t = threadIdx.x;
    int b = t & 31, q = t >> 5;
    float sa = 0.f, sb = 0.f;
    for (int j = 0; j < 8; ++j) {
        int blk = q * 8 + j;
        f32x2 v = *(const f32x2*)(part_ab + (((size_t)i * NB + blk) * BSZ + b) * 2);
        sa += v.x;
        sb += v.y;
    }
    __shared__ float ra[8][32], rb[8][32];
    ra[q][b] = sa;
    rb[q][b] = sb;
    __syncthreads();
    if (q == 0) {
        for (int j = 1; j < 8; ++j) { sa += ra[j][b]; sb += rb[j][b]; }
        a_arr[i * BSZ + b] = sa;
        b_arr[i * BSZ + b] = sb;
    }
}

// ---------------- attention: 8 queries per block, one batch per block.y (bf16 hist) ----------------
__global__ __launch_bounds__(256) void attn_kernel(const float* __restrict__ a_arr,
                                                   const float* __restrict__ b_arr,
                                                   const u16* __restrict__ hb_hist,
                                                   u16* __restrict__ ctx_bf) {
    int b = blockIdx.y;
    int i0 = blockIdx.x * 8;
    int t = threadIdx.x;
    __shared__ float att[8][256];
    __shared__ float red[256];

    float bt = b_arr[t * BSZ + b];
    for (int q = 0; q < 8; ++q) {
        int iq = i0 + q;
        att[q][t] = (t <= iq) ? tanhf(a_arr[iq * BSZ + b] + bt) : -INFINITY;
    }
    __syncthreads();
    for (int q = 0; q < 8; ++q) {
        int iq = i0 + q;
        red[t] = att[q][t];
        __syncthreads();
        for (int s = 128; s > 0; s >>= 1) {
            if (t < s) red[t] = fmaxf(red[t], red[t + s]);
            __syncthreads();
        }
        float m = red[0];
        __syncthreads();
        float e = (t <= iq) ? expf(att[q][t] - m) : 0.f;
        red[t] = e;
        __syncthreads();
        for (int s = 128; s > 0; s >>= 1) {
            if (t < s) red[t] += red[t + s];
            __syncthreads();
        }
        float sum = red[0];
        __syncthreads();
        att[q][t] = e / sum;
        __syncthreads();
    }

    int hc = t * 4;
    f32x4 accq[8];
    f32x4 zv = {0.f, 0.f, 0.f, 0.f};
    for (int q = 0; q < 8; ++q) accq[q] = zv;
    int imax = i0 + 7;
    for (int t2 = 0; t2 <= imax; ++t2) {
        u16x4 hq = *(const u16x4*)(hb_hist + (size_t)(t2 + 1) * (BSZ * HID) + (size_t)b * HID + hc);
        f32x4 hv = {BF2F(hq.x), BF2F(hq.y), BF2F(hq.z), BF2F(hq.w)};
        for (int q = 0; q < 8; ++q) accq[q] += hv * att[q][t2];
    }
    for (int q = 0; q < 8; ++q) {
        size_t row = (size_t)(i0 + q) * BSZ + b;
        u16x4 o = {f2bf(accq[q].x), f2bf(accq[q].y), f2bf(accq[q].z), f2bf(accq[q].w)};
        *(u16x4*)(ctx_bf + row * HID + hc) = o;
    }
}

// ---------------- in-place log_softmax over rows of [8192][10000], register-cached ----------------
__global__ __launch_bounds__(256) void logsoftmax_kernel(float* __restrict__ x, int V) {
    int row = blockIdx.x;
    float* p = x + (size_t)row * V;
    __shared__ float red[256];
    int t = threadIdx.x;
    float frag[40];
    float m = -INFINITY;
#pragma unroll
    for (int k = 0; k < 40; ++k) {
        int j = t + k * 256;
        if (j < VOC) {
            frag[k] = p[j];
            m = fmaxf(m, frag[k]);
        }
    }
    red[t] = m;
    __syncthreads();
    for (int s = 128; s > 0; s >>= 1) {
        if (t < s) red[t] = fmaxf(red[t], red[t + s]);
        __syncthreads();
    }
    m = red[0];
    __syncthreads();
    float sum = 0.f;
#pragma unroll
    for (int k = 0; k < 40; ++k) {
        int j = t + k * 256;
        if (j < VOC) sum += __expf(frag[k] - m);
    }
    red[t] = sum;
    __syncthreads();
    for (int s = 128; s > 0; s >>= 1) {
        if (t < s) red[t] += red[t + s];
        __syncthreads();
    }
    float lse = m + logf(red[0]);
#pragma unroll
    for (int k = 0; k < 40; ++k) {
        int j = t + k * 256;
        if (j < VOC) p[j] = frag[k] - lse;
    }
}

extern "C" void kernel_launch(void* const* d_in, const int* in_sizes, int n_in,
                              void* d_out, int out_size, void* d_ws, size_t ws_size,
                              hipStream_t stream) {
    const int* ids = (const int*)d_in[0];
    const float* h0 = (const float*)d_in[1];
    const float* c0 = (const float*)d_in[2];
    const float* emb_w = (const float*)d_in[3];
    const float* w_ih = (const float*)d_in[4];
    const float* w_hh = (const float*)d_in[5];
    const float* dec_w = (const float*)d_in[6];
    const float* dec_b = (const float*)d_in[7];
    const float* Wv = (const float*)d_in[8];
    const float* Uv = (const float*)d_in[9];

    char* p = (char*)d_ws;
    auto alloc = [&](size_t bytes) {
        void* r = (void*)p;
        p += (bytes + 255) & ~(size_t)255;
        return r;
    };
    u16* w_ih_bf = (u16*)alloc((size_t)G4 * NIN * 2);                 // 8 MiB
    u16* w_hh_bf = (u16*)alloc((size_t)G4 * HID * 2);                 // 8 MiB
    u16* dec_w_bf = (u16*)alloc((size_t)VOC * HID * 2);               // 20 MiB
    char* hbreg = (char*)alloc((size_t)(L_SEQ + 1) * BSZ * HID * 2);  // 16.84 MiB: A_emb -> hb_hist
    u16* ctx_bf = (u16*)alloc((size_t)MROWS * HID * 2);               // 16 MiB
    float* part_ab = (float*)alloc((size_t)L_SEQ * NB * BSZ * 2 * 4); // 4 MiB
    float* a_arr = (float*)alloc((size_t)L_SEQ * BSZ * 4);
    float* b_arr = (float*)alloc((size_t)L_SEQ * BSZ * 4);

    u16* A_emb = (u16*)hbreg;    // phase-1 only
    u16* hb_hist = (u16*)hbreg;  // recurrence
    float* out = (float*)d_out;
    float* gxT = out;  // transposed gx [64][256][4][16][32] f32 in d_out until logits overwrite
    float* out_tail = out + (size_t)MROWS * VOC;

    // phase 1: conversions + gx GEMM
    cvt_bf16_kernel<<<G4 * NIN / 1024, 256, 0, stream>>>(w_ih, w_ih_bf, G4 * NIN / 4);
    cvt_bf16_kernel<<<G4 * HID / 1024, 256, 0, stream>>>(w_hh, w_hh_bf, G4 * HID / 4);
    cvt_bf16_kernel<<<(VOC * HID / 4 + 255) / 256, 256, 0, stream>>>(dec_w, dec_w_bf, VOC * HID / 4);
    gather_emb_kernel<<<MROWS, 256, 0, stream>>>(ids, emb_w, A_emb);
    gemm_gxT_kernel<<<dim3(MROWS / 128, G4 / 128), 256, 0, stream>>>(A_emb, w_ih_bf, gxT);

    // phase 2: sentinel-fill slots 1..256, h(0) into slot 0 (A_emb dead now)
    hipMemsetAsync(hb_hist + (size_t)BSZ * HID, 0xFF, (size_t)L_SEQ * BSZ * HID * 2, stream);
    cvt_bf16_kernel<<<BSZ * HID / 1024, 256, 0, stream>>>(h0, hb_hist, BSZ * HID / 4);

    // phase 3: persistent recurrence (cooperative, 64 blocks; r4-exact protocol)
    {
        const float* c0a = c0;
        const u16* whha = w_hh_bf;
        const float* gxa = gxT;
        const float* Wa = Wv;
        const float* Ua = Uv;
        u16* hba = hb_hist;
        float* tail = out_tail;
        float* pab = part_ab;
        void* args[] = {&c0a, &whha, &gxa, &Wa, &Ua, &hba, &tail, &pab};
        hipLaunchCooperativeKernel((const void*)lstm_seq_kernel, dim3(NB), dim3(256), args, 0,
                                   stream);
    }
    // phase 4: tail pipeline
    reduce_ab_kernel<<<L_SEQ, 256, 0, stream>>>(part_ab, a_arr, b_arr);
    attn_kernel<<<dim3(L_SEQ / 8, BSZ), 256, 0, stream>>>(a_arr, b_arr, hb_hist, ctx_bf);
    gemm_bt_kernel<<<dim3(MROWS / 128, (VOC + 127) / 128), 256, 0, stream>>>(ctx_bf, dec_w_bf, out,
                                                                             dec_b, MROWS, VOC, HID);
    logsoftmax_kernel<<<MROWS, 256, 0, stream>>>(out, VOC);
}